// Round 5
// baseline (966.808 us; speedup 1.0000x reference)
//
#include <hip/hip_runtime.h>
#include <hip/hip_bf16.h>

namespace {

constexpr int TT = 150;

__device__ __forceinline__ float dot4(float4 a, float4 b) {
  return a.x*b.x + a.y*b.y + a.z*b.z + a.w*b.w;
}
__device__ __forceinline__ float bflo(unsigned u) {   // low bf16 -> f32 (exact)
  return __uint_as_float(u << 16);
}
__device__ __forceinline__ float bfhi(unsigned u) {   // high bf16 -> f32 (exact)
  return __uint_as_float(u & 0xffff0000u);
}
__device__ __forceinline__ unsigned short bf16bits(float v) {
  __hip_bfloat16 h = __float2bfloat16(v);
  return *reinterpret_cast<unsigned short*>(&h);
}
// dot of 8 packed-bf16 basis values with cp[0..7]
__device__ __forceinline__ float dp8(uint4 u, const float* cp) {
  float s;
  s  = bflo(u.x)*cp[0]; s += bfhi(u.x)*cp[1];
  s += bflo(u.y)*cp[2]; s += bfhi(u.y)*cp[3];
  s += bflo(u.z)*cp[4]; s += bfhi(u.z)*cp[5];
  s += bflo(u.w)*cp[6]; s += bfhi(u.w)*cp[7];
  return s;
}

// ---------------- pre-pass: ctrl = relu(act@w1+b1)@w2 + b2 -> o4 region ----
// grid 256 x 256 threads (4 waves). Wave handles bt = blockIdx*4+w + it*1024.
// Lane c<60 computes output col-pair (2c, 2c+1); writes float2 to o4[bt*120+2c].
__launch_bounds__(256, 1)
__global__ void ctrl_pre(const float* __restrict__ actp,  // (B*T,10)
                         const float* __restrict__ w1,    // (10,60)
                         const float* __restrict__ b1,    // (60)
                         const float* __restrict__ w2,    // (60,120)
                         const float* __restrict__ b2,    // (120)
                         float* __restrict__ out)
{
  __shared__ float w1s[640];   // [a][j<64]
  __shared__ float b1s[64];
  __shared__ float w2p[7680];  // [j][c<64][2] = w2[j][2c+p]
  __shared__ float b2s[128];
  __shared__ float hw[256];    // [wave][j<64]

  const int tid = threadIdx.x;
  for (int idx = tid; idx < 640; idx += 256) {
    const int j = idx & 63, a = idx >> 6;
    w1s[idx] = (j < 60) ? w1[a*60 + j] : 0.f;
  }
  for (int idx = tid; idx < 7680; idx += 256) {
    const int p = idx & 1, c = (idx >> 1) & 63, j = idx >> 7;
    const int col = 2*c + p;
    w2p[idx] = (j < 60 && col < 120) ? w2[j*120 + col] : 0.f;
  }
  if (tid < 64)  b1s[tid] = (tid < 60)  ? b1[tid] : 0.f;
  if (tid < 128) b2s[tid] = (tid < 120) ? b2[tid] : 0.f;
  __syncthreads();

  const int w = tid >> 6, lane = tid & 63;
  float* o4 = out + 46080000L;

  for (int it = 0; it < 150; ++it) {
    const int bt = (blockIdx.x*4 + w) + it*1024;   // flat b*T+t, covers 153600
    float av = (lane < 10) ? actp[(long)bt*10 + lane] : 0.f;
    float hj = b1s[lane];
    #pragma unroll
    for (int a = 0; a < 10; ++a) hj += __shfl(av, a) * w1s[a*64 + lane];
    hj = fmaxf(hj, 0.f);
    hw[w*64 + lane] = (lane < 60) ? hj : 0.f;

    float s0 = 0.f, s1 = 0.f;
    if (lane < 60) { s0 = b2s[2*lane]; s1 = b2s[2*lane + 1]; }
    for (int j = 0; j < 60; ++j) {
      const float h = hw[w*64 + j];
      s0 += h * w2p[j*128 + 2*lane];
      s1 += h * w2p[j*128 + 2*lane + 1];
    }
    if (lane < 60) {
      float2* dst = (float2*)(o4 + (long)bt*120 + 2*lane);
      *dst = make_float2(s0, s1);
    }
  }
}

// ---------------- main scan kernel ----------------
// Block = 256 threads = 4 waves. lane=(r,b): r=lane>>2, b=lane&3. Wave w owns
// rows i=16w+r. grid=256 -> B=1024. Basis in LDS as packed bf16x2 (swizzled).
// ctrl read from o4 (written by prepass), overwritten with prior_means here.
__launch_bounds__(256, 1)
__global__ void acrkn(const float* __restrict__ lob,   // (B,T,60)
                      const float* __restrict__ ovr,   // (B,T,60)
                      const float* __restrict__ im,    // (B,120)
                      const float* __restrict__ icu,   // (B,60)
                      const float* __restrict__ icl,   // (B,60)
                      const float* __restrict__ ics,   // (B,60)
                      const float* __restrict__ tm11,  // (15,60,60)
                      const float* __restrict__ tm12,
                      const float* __restrict__ tm21,
                      const float* __restrict__ tm22,
                      const float* __restrict__ cw,    // (120,15)
                      const float* __restrict__ cb,    // (15)
                      const float* __restrict__ ltc,   // (120)
                      float* __restrict__ out)
{
  // Band-compacted basis, packed bf16x2: u32 word q of uint4 slot s holds
  // k=(8s+2q, 8s+2q+1) of tm_mat[k][i][i+d-3]. Physical slot sp = s^((i>>2)&1)
  // (bank de-alias for the 32B row stride). uint4 index: (mat*7+d)*120 + i*2 + sp.
  __shared__ __align__(16) unsigned m4b[13440];  // 53760 B
  __shared__ __align__(16) float cwc[2048];      // f4 = c*128+p: p<60 col p; 64<=p<124 col p-4
  __shared__ __align__(16) float stat[1440];     // [vec][row 0..71][b], row=idx+3
  __shared__ float parts[256];                   // [w][b][k 0..15]
  __shared__ float cbs[16];

  const int tid = threadIdx.x;

  // ---------------- one-time LDS staging ----------------
  for (int idx = tid; idx < 13440; idx += 256) {
    const int c2 = idx & 7;          // logical k-pair index
    int rest = idx >> 3;
    const int i = rest % 60;  rest /= 60;
    const int d = rest % 7;
    const int mat = rest / 7;
    const int k0 = 2*c2;
    const int j = i + d - 3;
    const float* tp = (mat == 0) ? tm11 : (mat == 1) ? tm12 : (mat == 2) ? tm21 : tm22;
    float ve = 0.f, vo = 0.f;
    if (j >= 0 && j < 60) {
      ve = tp[(k0*60 + i)*60 + j];
      if (k0 + 1 < 15) vo = tp[((k0+1)*60 + i)*60 + j];
    }
    const unsigned u = ((unsigned)bf16bits(vo) << 16) | (unsigned)bf16bits(ve);
    const int s = c2 >> 2, q = c2 & 3;
    const int sp = s ^ ((i >> 2) & 1);
    m4b[(((mat*7 + d)*60 + i)*2 + sp)*4 + q] = u;
  }
  for (int f4 = tid; f4 < 512; f4 += 256) {
    const int p = f4 & 127, c = f4 >> 7;
    const int col = (p < 60) ? p : ((p >= 64 && p < 124) ? (p - 4) : -1);
    float v0 = 0.f, v1 = 0.f, v2 = 0.f, v3 = 0.f;
    if (col >= 0) {
      const int k0 = c*4;
      v0 = cw[col*15 + k0+0];
      v1 = cw[col*15 + k0+1];
      v2 = cw[col*15 + k0+2];
      v3 = (k0+3 < 15) ? cw[col*15 + k0+3] : 0.f;
    }
    ((float4*)cwc)[f4] = make_float4(v0, v1, v2, v3);
  }
  for (int idx = tid; idx < 1440; idx += 256) stat[idx] = 0.f;
  if (tid < 16) cbs[tid] = (tid < 15) ? cb[tid] : 0.f;

  const int lane = tid & 63;
  const int w = tid >> 6;
  const int r = lane >> 2;
  const int b = lane & 3;
  const int iraw = w*16 + r;
  const bool valid = (iraw < 60);
  const int ii = valid ? iraw : 0;
  const int gb = blockIdx.x*4 + b;
  const int swz = (ii >> 2) & 1;

  // carries (prior state entering step t)
  float mu_c = 0.f, ml_c = 0.f, cu_c = 1.f, cl_c = 1.f, cs_c = 0.f;
  float tcu_r = 1.f, tcl_r = 1.f;
  if (valid) {
    mu_c = im[gb*120 + ii];
    ml_c = im[gb*120 + 60 + ii];
    cu_c = icu[gb*60 + ii];
    cl_c = icl[gb*60 + ii];
    cs_c = ics[gb*60 + ii];
    const float l0 = ltc[ii], l1 = ltc[60 + ii];
    tcu_r = (l0 >= 0.f) ? l0 + 1.f : __expf(l0);   // elup1
    tcl_r = (l1 >= 0.f) ? l1 + 1.f : __expf(l1);
  }

  const uint4*  m4u  = (const uint4*)m4b;
  const float4* cwc4 = (const float4*)cwc;

  float* o0 = out;                 // post_means  (B,T,120)
  float* o1 = out + 18432000L;     // pcu (B,T,60)
  float* o2 = out + 27648000L;     // pcl
  float* o3 = out + 36864000L;     // pcs
  float* o4 = out + 46080000L;     // prior_means (B,T,120) -- holds ctrl now
  float* o5 = out + 64512000L;     // ncu
  float* o6 = out + 73728000L;     // ncl
  float* o7 = out + 82944000L;     // ncs

  __syncthreads();

  for (int t = 0; t < TT; ++t) {
    const long ob120 = ((long)gb*TT + t)*120;
    // ---- ctrl (precomputed) — issue loads early ----
    float ctrl_u = 0.f, ctrl_l = 0.f;
    if (valid) { ctrl_u = o4[ob120 + ii]; ctrl_l = o4[ob120 + 60 + ii]; }

    // ---- phase A: Kalman update ----
    const long ib = (long)gb*(TT*60) + t*60 + ii;
    float obs = 0.f, ovv = 1.f;
    if (valid) { obs = lob[ib]; ovv = ovr[ib]; }
    const float denom = cu_c + ovv;
    const float inv = 1.0f / denom;
    const float qu = cu_c * inv;
    const float ql = cs_c * inv;
    const float res = obs - mu_c;
    float pm_u = mu_c + qu*res;
    float pm_l = ml_c + ql*res;
    const float f1 = 1.f - qu;
    float pcu = f1*cu_c, pcs = f1*cs_c, pcl = cl_c - ql*cs_c;
    if (!valid) { pm_u = 0.f; pm_l = 0.f; pcu = 0.f; pcs = 0.f; pcl = 0.f; }

    // ---- stage posterior state for banded neighbor access ----
    if (valid) {
      stat[(0*72 + ii + 3)*4 + b] = pm_u;
      stat[(1*72 + ii + 3)*4 + b] = pm_l;
      stat[(2*72 + ii + 3)*4 + b] = pcu;
      stat[(3*72 + ii + 3)*4 + b] = pcs;
      stat[(4*72 + ii + 3)*4 + b] = pcl;
    }

    // ---- coeff logit partials ----
    float p[16];
    #pragma unroll
    for (int k = 0; k < 16; ++k) p[k] = 0.f;
    #pragma unroll
    for (int c = 0; c < 4; ++c) {
      const float4 wu = cwc4[c*128 + ii];
      const float4 wl = cwc4[c*128 + 64 + ii];
      p[c*4+0] += pm_u*wu.x + pm_l*wl.x;
      p[c*4+1] += pm_u*wu.y + pm_l*wl.y;
      p[c*4+2] += pm_u*wu.z + pm_l*wl.z;
      p[c*4+3] += pm_u*wu.w + pm_l*wl.w;
    }
    #pragma unroll
    for (int m = 4; m <= 32; m <<= 1) {
      #pragma unroll
      for (int k = 0; k < 16; ++k) p[k] += __shfl_xor(p[k], m);
    }
    if (r == 0) {
      #pragma unroll
      for (int k = 0; k < 16; ++k) parts[(w*4 + b)*16 + k] = p[k];
    }
    __syncthreads();   // B1

    // ---- phase C: finalize logits + softmax ----
    float q[16];
    #pragma unroll
    for (int k = 0; k < 16; ++k) q[k] = cbs[k];
    #pragma unroll
    for (int ww = 0; ww < 4; ++ww) {
      #pragma unroll
      for (int k = 0; k < 16; ++k) q[k] += parts[(ww*4 + b)*16 + k];
    }
    float mx = q[0];
    #pragma unroll
    for (int k = 1; k < 15; ++k) mx = fmaxf(mx, q[k]);
    float ce[16];
    float ssum = 0.f;
    #pragma unroll
    for (int k = 0; k < 15; ++k) { ce[k] = __expf(q[k] - mx); ssum += ce[k]; }
    const float rs = 1.f / ssum;
    #pragma unroll
    for (int k = 0; k < 15; ++k) ce[k] *= rs;
    ce[15] = 0.f;

    // ---- banded transition rows from packed-bf16 basis ----
    float t11[7], t12[7], t21[7], t22[7];
    #pragma unroll
    for (int d = 0; d < 7; ++d) {
      const int rb0 = (0*7 + d)*120 + ii*2;
      const int rb1 = (1*7 + d)*120 + ii*2;
      const int rb2 = (2*7 + d)*120 + ii*2;
      const int rb3 = (3*7 + d)*120 + ii*2;
      const uint4 a0 = m4u[rb0 + swz], b0 = m4u[rb0 + 1 - swz];
      const uint4 a1 = m4u[rb1 + swz], b1x = m4u[rb1 + 1 - swz];
      const uint4 a2 = m4u[rb2 + swz], b2x = m4u[rb2 + 1 - swz];
      const uint4 a3 = m4u[rb3 + swz], b3x = m4u[rb3 + 1 - swz];
      t11[d] = dp8(a0, ce) + dp8(b0,  ce + 8);
      t12[d] = dp8(a1, ce) + dp8(b1x, ce + 8);
      t21[d] = dp8(a2, ce) + dp8(b2x, ce + 8);
      t22[d] = dp8(a3, ce) + dp8(b3x, ce + 8);
    }

    // ---- banded mat-vec: prior mean + covariances ----
    float nmu = ctrl_u, nml = ctrl_l;
    float ncu = tcu_r, ncl = tcl_r, ncs = 0.f;
    #pragma unroll
    for (int d = 0; d < 7; ++d) {
      const int si = (ii + d)*4 + b;
      const float mun  = stat[si];
      const float mln  = stat[288  + si];
      const float pcun = stat[576  + si];
      const float pcsn = stat[864  + si];
      const float pcln = stat[1152 + si];
      const float a11 = t11[d], a12 = t12[d], a21 = t21[d], a22 = t22[d];
      nmu += a11*mun + a12*mln;
      nml += a21*mun + a22*mln;
      ncu += a11*a11*pcun + 2.f*a11*a12*pcsn + a12*a12*pcln;
      ncl += a21*a21*pcun + 2.f*a21*a22*pcsn + a22*a22*pcln;
      ncs += a21*a11*pcun + (a22*a11 + a21*a12)*pcsn + a22*a12*pcln;
    }

    // ---- outputs (float32) ----
    if (valid) {
      const long ob60 = ((long)gb*TT + t)*60;
      o0[ob120 + ii]      = pm_u;
      o0[ob120 + 60 + ii] = pm_l;
      o1[ob60 + ii] = pcu;
      o2[ob60 + ii] = pcl;
      o3[ob60 + ii] = pcs;
      o4[ob120 + ii]      = nmu;     // overwrite ctrl with prior_means
      o4[ob120 + 60 + ii] = nml;
      o5[ob60 + ii] = ncu;
      o6[ob60 + ii] = ncl;
      o7[ob60 + ii] = ncs;
    }

    // ---- carry ----
    mu_c = nmu; ml_c = nml; cu_c = ncu; cl_c = ncl; cs_c = ncs;
    __syncthreads();   // B3: protect stat/parts rewrite next iter
  }
}

} // namespace

extern "C" void kernel_launch(void* const* d_in, const int* in_sizes, int n_in,
                              void* d_out, int out_size, void* d_ws, size_t ws_size,
                              hipStream_t stream) {
  (void)in_sizes; (void)n_in; (void)d_ws; (void)ws_size; (void)out_size;
  const float* lob  = (const float*)d_in[0];
  const float* ovr  = (const float*)d_in[1];
  const float* actp = (const float*)d_in[2];
  const float* im   = (const float*)d_in[3];
  const float* icu  = (const float*)d_in[4];
  const float* icl  = (const float*)d_in[5];
  const float* ics  = (const float*)d_in[6];
  const float* tm11 = (const float*)d_in[7];
  const float* tm12 = (const float*)d_in[8];
  const float* tm21 = (const float*)d_in[9];
  const float* tm22 = (const float*)d_in[10];
  const float* cw   = (const float*)d_in[11];
  const float* cb   = (const float*)d_in[12];
  const float* w1   = (const float*)d_in[13];
  const float* b1   = (const float*)d_in[14];
  const float* w2   = (const float*)d_in[15];
  const float* b2   = (const float*)d_in[16];
  const float* ltc  = (const float*)d_in[17];

  ctrl_pre<<<dim3(256), dim3(256), 0, stream>>>(actp, w1, b1, w2, b2, (float*)d_out);
  acrkn<<<dim3(256), dim3(256), 0, stream>>>(
      lob, ovr, im, icu, icl, ics,
      tm11, tm12, tm21, tm22, cw, cb, ltc,
      (float*)d_out);
}

// Round 6
// 775.076 us; speedup vs baseline: 1.2474x; 1.2474x over previous
//
#include <hip/hip_runtime.h>
#include <hip/hip_bf16.h>

namespace {

constexpr int TT = 150;

__device__ __forceinline__ float dot4(float4 a, float4 b) {
  return a.x*b.x + a.y*b.y + a.z*b.z + a.w*b.w;
}
__device__ __forceinline__ unsigned short bf16bits(float v) {
  __hip_bfloat16 h = __float2bfloat16(v);
  return *reinterpret_cast<unsigned short*>(&h);
}
// f32 += dot of a bf16 pair (packed u32) with a bf16 pair (packed u32)
__device__ __forceinline__ float dot2bf(unsigned a, unsigned b, float c) {
  float d;
  asm("v_dot2_f32_bf16 %0, %1, %2, %3" : "=v"(d) : "v"(a), "v"(b), "v"(c));
  return d;
}
// 16-wide bf16 dot: two uint4 slots (k 0..7, 8..15) against cepk[0..7]
__device__ __forceinline__ float tdot(uint4 a, uint4 b, const unsigned* cp) {
  float s = 0.f;
  s = dot2bf(a.x, cp[0], s); s = dot2bf(a.y, cp[1], s);
  s = dot2bf(a.z, cp[2], s); s = dot2bf(a.w, cp[3], s);
  s = dot2bf(b.x, cp[4], s); s = dot2bf(b.y, cp[5], s);
  s = dot2bf(b.z, cp[6], s); s = dot2bf(b.w, cp[7], s);
  return s;
}

// t-build + banded matvec partials for d in [D0, D0+ND)
template<int D0, int ND>
__device__ __forceinline__ void tmv_part(const uint4* m4u, const unsigned* cepk,
                                         const float* stat, int ii, int b, int swz,
                                         float rv[5]) {
  #pragma unroll
  for (int dd = 0; dd < ND; ++dd) {
    const int d = D0 + dd;
    const int ba = (0*7 + d)*120 + ii*2;
    const int bb = (1*7 + d)*120 + ii*2;
    const int bc = (2*7 + d)*120 + ii*2;
    const int bd = (3*7 + d)*120 + ii*2;
    const uint4 xa = m4u[ba + swz], ya = m4u[ba + 1 - swz];
    const uint4 xb = m4u[bb + swz], yb = m4u[bb + 1 - swz];
    const uint4 xc = m4u[bc + swz], yc = m4u[bc + 1 - swz];
    const uint4 xd = m4u[bd + swz], yd = m4u[bd + 1 - swz];
    const float a11 = tdot(xa, ya, cepk);
    const float a12 = tdot(xb, yb, cepk);
    const float a21 = tdot(xc, yc, cepk);
    const float a22 = tdot(xd, yd, cepk);
    const int si = (ii + d)*4 + b;
    const float mun  = stat[si];
    const float mln  = stat[288  + si];
    const float pcun = stat[576  + si];
    const float pcsn = stat[864  + si];
    const float pcln = stat[1152 + si];
    rv[0] += a11*mun + a12*mln;
    rv[1] += a21*mun + a22*mln;
    rv[2] += a11*a11*pcun + 2.f*a11*a12*pcsn + a12*a12*pcln;
    rv[3] += a21*a21*pcun + 2.f*a21*a22*pcsn + a22*a22*pcln;
    rv[4] += a21*a11*pcun + (a22*a11 + a21*a12)*pcsn + a22*a12*pcln;
  }
}

// ---------------- pre-pass: ctrl = relu(act@w1+b1)@w2 + b2 -> o4 region ----
// grid 2048 x 256 (4 waves); wave handles bt = blockIdx*4+w + it*8192.
// w2 tiled lane-major (w2pk[p][j4][lane][4]) so the j-loop is bank-tiled b128.
__launch_bounds__(256, 4)
__global__ void ctrl_pre(const float* __restrict__ actp,  // (B*T,10)
                         const float* __restrict__ w1,    // (10,60)
                         const float* __restrict__ b1,    // (60)
                         const float* __restrict__ w2,    // (60,120)
                         const float* __restrict__ b2,    // (120)
                         float* __restrict__ out)
{
  __shared__ float w1s[640];              // [a][j<64]
  __shared__ float b1s[64];
  __shared__ __align__(16) float w2pk[7680]; // [p][j4][lane][e] = w2[4j4+e][2*lane+p]
  __shared__ float b2s[128];
  __shared__ __align__(16) float hbuf[256];  // [w][j<64]

  const int tid = threadIdx.x;
  for (int idx = tid; idx < 640; idx += 256) {
    const int j = idx & 63, a = idx >> 6;
    w1s[idx] = (j < 60) ? w1[a*60 + j] : 0.f;
  }
  for (int idx = tid; idx < 7680; idx += 256) {
    const int e = idx & 3;
    const int l = (idx >> 2) & 63;
    const int rest = idx >> 8;
    const int j4 = rest % 15;
    const int p  = rest / 15;
    w2pk[idx] = (l < 60) ? w2[(4*j4 + e)*120 + 2*l + p] : 0.f;
  }
  if (tid < 64)  b1s[tid] = (tid < 60)  ? b1[tid] : 0.f;
  if (tid < 128) b2s[tid] = (tid < 120) ? b2[tid] : 0.f;
  __syncthreads();

  const int w = tid >> 6, lane = tid & 63;
  float* o4 = out + 46080000L;
  const float4* w2pk4 = (const float4*)w2pk;
  const float4* hb4   = (const float4*)hbuf;

  for (int it = 0; it < 19; ++it) {
    const long bt = (long)(blockIdx.x*4 + w) + (long)it*8192;
    if (bt >= 153600L) break;
    const float av = (lane < 10) ? actp[bt*10 + lane] : 0.f;
    float hj = b1s[lane];
    #pragma unroll
    for (int a = 0; a < 10; ++a) hj += __shfl(av, a) * w1s[a*64 + lane];
    hbuf[w*64 + lane] = (lane < 60) ? fmaxf(hj, 0.f) : 0.f;
    // intra-wave LDS RAW: in-order lgkmcnt, compiler inserts the wait

    float s0 = 0.f, s1 = 0.f;
    if (lane < 60) { s0 = b2s[2*lane]; s1 = b2s[2*lane + 1]; }
    #pragma unroll
    for (int j4 = 0; j4 < 15; ++j4) {
      const float4 hq = hb4[w*16 + j4];
      s0 += dot4(hq, w2pk4[(0*15 + j4)*64 + lane]);
      s1 += dot4(hq, w2pk4[(1*15 + j4)*64 + lane]);
    }
    if (lane < 60) ((float2*)(o4 + bt*120))[lane] = make_float2(s0, s1);
  }
}

// ---------------- main scan kernel ----------------
// 512 threads = 8 waves. group g = w>>2: g0 -> Kalman/stat/logits + d{0..3};
// g1 -> d{4,5,6}. lane=(r,b): iraw=(w&3)*16+r, b=lane&3. grid 256 -> B=1024.
// Partials combined through red[]; 2 barriers/step.
__launch_bounds__(512, 2)
__global__ void acrkn(const float* __restrict__ lob,   // (B,T,60)
                      const float* __restrict__ ovr,   // (B,T,60)
                      const float* __restrict__ im,    // (B,120)
                      const float* __restrict__ icu,   // (B,60)
                      const float* __restrict__ icl,   // (B,60)
                      const float* __restrict__ ics,   // (B,60)
                      const float* __restrict__ tm11,  // (15,60,60)
                      const float* __restrict__ tm12,
                      const float* __restrict__ tm21,
                      const float* __restrict__ tm22,
                      const float* __restrict__ cw,    // (120,15)
                      const float* __restrict__ cb,    // (15)
                      const float* __restrict__ ltc,   // (120)
                      float* __restrict__ out)
{
  // basis packed bf16x2; uint4 slot index (mat*7+d)*120 + i*2 + sp, sp=s^((i>>2)&1)
  __shared__ __align__(16) unsigned m4b[13440];  // 53760 B
  __shared__ __align__(16) float cwc[2048];      // logits weights (f4 = c*128+p)
  __shared__ __align__(16) float stat[1440];     // [vec][row 0..71][b]
  __shared__ __align__(16) float parts[256];     // [wq][b][k16]
  __shared__ __align__(16) float red[2560];      // [g][v][i<64][b]
  __shared__ float cbs[16];

  const int tid = threadIdx.x;

  // ---------------- one-time LDS staging ----------------
  for (int idx = tid; idx < 13440; idx += 512) {
    const int c2 = idx & 7;
    int rest = idx >> 3;
    const int i = rest % 60;  rest /= 60;
    const int d = rest % 7;
    const int mat = rest / 7;
    const int k0 = 2*c2;
    const int j = i + d - 3;
    const float* tp = (mat == 0) ? tm11 : (mat == 1) ? tm12 : (mat == 2) ? tm21 : tm22;
    float ve = 0.f, vo = 0.f;
    if (j >= 0 && j < 60) {
      ve = tp[(k0*60 + i)*60 + j];
      if (k0 + 1 < 15) vo = tp[((k0+1)*60 + i)*60 + j];
    }
    const unsigned u = ((unsigned)bf16bits(vo) << 16) | (unsigned)bf16bits(ve);
    const int s = c2 >> 2, q = c2 & 3;
    const int sp = s ^ ((i >> 2) & 1);
    m4b[(((mat*7 + d)*60 + i)*2 + sp)*4 + q] = u;
  }
  for (int f4 = tid; f4 < 512; f4 += 512) {
    const int p = f4 & 127, c = f4 >> 7;
    const int col = (p < 60) ? p : ((p >= 64 && p < 124) ? (p - 4) : -1);
    float v0 = 0.f, v1 = 0.f, v2 = 0.f, v3 = 0.f;
    if (col >= 0) {
      const int k0 = c*4;
      v0 = cw[col*15 + k0+0];
      v1 = cw[col*15 + k0+1];
      v2 = cw[col*15 + k0+2];
      v3 = (k0+3 < 15) ? cw[col*15 + k0+3] : 0.f;
    }
    ((float4*)cwc)[f4] = make_float4(v0, v1, v2, v3);
  }
  for (int idx = tid; idx < 1440; idx += 512) stat[idx] = 0.f;
  if (tid < 16) cbs[tid] = (tid < 15) ? cb[tid] : 0.f;

  const int w = tid >> 6;
  const int g = w >> 2;            // 0: front-end + d0..3 | 1: d4..6
  const int wq = w & 3;
  const int lane = tid & 63;
  const int r = lane >> 2;
  const int b = lane & 3;
  const int iraw = wq*16 + r;
  const bool valid = (iraw < 60);
  const int ii = valid ? iraw : 0;
  const int gb = blockIdx.x*4 + b;
  const int swz = (ii >> 2) & 1;

  // carries (used by g0 only; g1 computes but never reads them)
  float mu_c = 0.f, ml_c = 0.f, cu_c = 1.f, cl_c = 1.f, cs_c = 0.f;
  float tcu_r = 1.f, tcl_r = 1.f;
  if (valid) {
    mu_c = im[gb*120 + ii];
    ml_c = im[gb*120 + 60 + ii];
    cu_c = icu[gb*60 + ii];
    cl_c = icl[gb*60 + ii];
    cs_c = ics[gb*60 + ii];
    const float l0 = ltc[ii], l1 = ltc[60 + ii];
    tcu_r = (l0 >= 0.f) ? l0 + 1.f : __expf(l0);   // elup1
    tcl_r = (l1 >= 0.f) ? l1 + 1.f : __expf(l1);
  }

  const uint4*  m4u    = (const uint4*)m4b;
  const float4* cwc4   = (const float4*)cwc;
  const float4* parts4 = (const float4*)parts;

  float* o0 = out;                 // post_means  (B,T,120)
  float* o1 = out + 18432000L;     // pcu (B,T,60)
  float* o2 = out + 27648000L;     // pcl
  float* o3 = out + 36864000L;     // pcs
  float* o4 = out + 46080000L;     // prior_means (B,T,120) -- ctrl until overwritten
  float* o5 = out + 64512000L;     // ncu
  float* o6 = out + 73728000L;     // ncl
  float* o7 = out + 82944000L;     // ncs

  __syncthreads();

  for (int t = 0; t < TT; ++t) {
    const long ob120 = ((long)gb*TT + t)*120;

    // ---- phase A ----
    float ctrl_u = 0.f, ctrl_l = 0.f;
    if (valid) { ctrl_u = o4[ob120 + ii]; ctrl_l = o4[ob120 + 60 + ii]; }  // both groups

    float pm_u = 0.f, pm_l = 0.f, pcu = 0.f, pcs = 0.f, pcl = 0.f;
    if (g == 0) {
      // Kalman update
      const long ib = (long)gb*(TT*60) + t*60 + ii;
      float obs = 0.f, ovv = 1.f;
      if (valid) { obs = lob[ib]; ovv = ovr[ib]; }
      const float denom = cu_c + ovv;
      const float inv = 1.0f / denom;
      const float qu = cu_c * inv;
      const float ql = cs_c * inv;
      const float res = obs - mu_c;
      pm_u = mu_c + qu*res;
      pm_l = ml_c + ql*res;
      const float f1 = 1.f - qu;
      pcu = f1*cu_c; pcs = f1*cs_c; pcl = cl_c - ql*cs_c;
      if (!valid) { pm_u = 0.f; pm_l = 0.f; pcu = 0.f; pcs = 0.f; pcl = 0.f; }

      if (valid) {
        stat[(0*72 + ii + 3)*4 + b] = pm_u;
        stat[(1*72 + ii + 3)*4 + b] = pm_l;
        stat[(2*72 + ii + 3)*4 + b] = pcu;
        stat[(3*72 + ii + 3)*4 + b] = pcs;
        stat[(4*72 + ii + 3)*4 + b] = pcl;
      }

      // logit partials + intra-wave butterfly over the 16 r-lanes
      float p[16];
      #pragma unroll
      for (int k = 0; k < 16; ++k) p[k] = 0.f;
      #pragma unroll
      for (int c = 0; c < 4; ++c) {
        const float4 wu = cwc4[c*128 + ii];
        const float4 wl = cwc4[c*128 + 64 + ii];
        p[c*4+0] += pm_u*wu.x + pm_l*wl.x;
        p[c*4+1] += pm_u*wu.y + pm_l*wl.y;
        p[c*4+2] += pm_u*wu.z + pm_l*wl.z;
        p[c*4+3] += pm_u*wu.w + pm_l*wl.w;
      }
      #pragma unroll
      for (int m = 4; m <= 32; m <<= 1) {
        #pragma unroll
        for (int k = 0; k < 16; ++k) p[k] += __shfl_xor(p[k], m);
      }
      if (r == 0) {
        float4* pw = (float4*)parts;
        #pragma unroll
        for (int c = 0; c < 4; ++c)
          pw[(wq*4 + b)*4 + c] = make_float4(p[4*c], p[4*c+1], p[4*c+2], p[4*c+3]);
      }
    }
    __syncthreads();   // B1

    // ---- phase C: softmax (all waves) ----
    float q[16];
    #pragma unroll
    for (int k = 0; k < 16; ++k) q[k] = cbs[k];
    #pragma unroll
    for (int ww = 0; ww < 4; ++ww) {
      #pragma unroll
      for (int c = 0; c < 4; ++c) {
        const float4 pv = parts4[(ww*4 + b)*4 + c];
        q[4*c+0] += pv.x; q[4*c+1] += pv.y; q[4*c+2] += pv.z; q[4*c+3] += pv.w;
      }
    }
    float mx = q[0];
    #pragma unroll
    for (int k = 1; k < 15; ++k) mx = fmaxf(mx, q[k]);
    float ce[16];
    float ssum = 0.f;
    #pragma unroll
    for (int k = 0; k < 15; ++k) { ce[k] = __expf(q[k] - mx); ssum += ce[k]; }
    const float rs = 1.f / ssum;
    #pragma unroll
    for (int k = 0; k < 15; ++k) ce[k] *= rs;
    ce[15] = 0.f;
    unsigned cepk[8];
    #pragma unroll
    for (int j = 0; j < 8; ++j)
      cepk[j] = ((unsigned)bf16bits(ce[2*j+1]) << 16) | (unsigned)bf16bits(ce[2*j]);

    // ---- t-build + matvec partials for this group's d-range ----
    float rv[5] = {0.f, 0.f, 0.f, 0.f, 0.f};
    if (g == 0) tmv_part<0, 4>(m4u, cepk, stat, ii, b, swz, rv);
    else        tmv_part<4, 3>(m4u, cepk, stat, ii, b, swz, rv);

    if (valid) {
      #pragma unroll
      for (int v = 0; v < 5; ++v) red[((g*5 + v)*64 + ii)*4 + b] = rv[v];
    }
    __syncthreads();   // B2

    // ---- phase D: combine + outputs ----
    const int rb = ii*4 + b;
    const float nmu = red[(0*64)*4 + rb]  + red[(5*64)*4 + rb]  + ctrl_u;
    const float nml = red[(1*64)*4 + rb]  + red[(6*64)*4 + rb]  + ctrl_l;
    const float ncu = red[(2*64)*4 + rb]  + red[(7*64)*4 + rb]  + tcu_r;
    const float ncl = red[(3*64)*4 + rb]  + red[(8*64)*4 + rb]  + tcl_r;
    const float ncs = red[(4*64)*4 + rb]  + red[(9*64)*4 + rb];

    if (valid) {
      const long ob60 = ((long)gb*TT + t)*60;
      if (g == 0) {
        o0[ob120 + ii]      = pm_u;
        o0[ob120 + 60 + ii] = pm_l;
        o1[ob60 + ii] = pcu;
        o2[ob60 + ii] = pcl;
        o3[ob60 + ii] = pcs;
      } else {
        o4[ob120 + ii]      = nmu;    // overwrite ctrl with prior_means
        o4[ob120 + 60 + ii] = nml;
        o5[ob60 + ii] = ncu;
        o6[ob60 + ii] = ncl;
        o7[ob60 + ii] = ncs;
      }
    }

    // carries (meaningful in g0 only)
    mu_c = nmu; ml_c = nml; cu_c = ncu; cl_c = ncl; cs_c = ncs;
    // no barrier here: stat/parts writes of next phase A are ordered after B2,
    // and all stat/parts reads happened before B2.
  }
}

} // namespace

extern "C" void kernel_launch(void* const* d_in, const int* in_sizes, int n_in,
                              void* d_out, int out_size, void* d_ws, size_t ws_size,
                              hipStream_t stream) {
  (void)in_sizes; (void)n_in; (void)d_ws; (void)ws_size; (void)out_size;
  const float* lob  = (const float*)d_in[0];
  const float* ovr  = (const float*)d_in[1];
  const float* actp = (const float*)d_in[2];
  const float* im   = (const float*)d_in[3];
  const float* icu  = (const float*)d_in[4];
  const float* icl  = (const float*)d_in[5];
  const float* ics  = (const float*)d_in[6];
  const float* tm11 = (const float*)d_in[7];
  const float* tm12 = (const float*)d_in[8];
  const float* tm21 = (const float*)d_in[9];
  const float* tm22 = (const float*)d_in[10];
  const float* cw   = (const float*)d_in[11];
  const float* cb   = (const float*)d_in[12];
  const float* w1   = (const float*)d_in[13];
  const float* b1   = (const float*)d_in[14];
  const float* w2   = (const float*)d_in[15];
  const float* b2   = (const float*)d_in[16];
  const float* ltc  = (const float*)d_in[17];

  ctrl_pre<<<dim3(2048), dim3(256), 0, stream>>>(actp, w1, b1, w2, b2, (float*)d_out);
  acrkn<<<dim3(256), dim3(512), 0, stream>>>(
      lob, ovr, im, icu, icl, ics,
      tm11, tm12, tm21, tm22, cw, cb, ltc,
      (float*)d_out);
}

// Round 7
// 725.164 us; speedup vs baseline: 1.3332x; 1.0688x over previous
//
#include <hip/hip_runtime.h>
#include <hip/hip_bf16.h>

namespace {

constexpr int TT = 150;

__device__ __forceinline__ float dot4(float4 a, float4 b) {
  return a.x*b.x + a.y*b.y + a.z*b.z + a.w*b.w;
}
__device__ __forceinline__ unsigned short bf16bits(float v) {
  __hip_bfloat16 h = __float2bfloat16(v);
  return *reinterpret_cast<unsigned short*>(&h);
}
// f32 += dot of a bf16 pair (packed u32) with a bf16 pair (packed u32)
__device__ __forceinline__ float dot2bf(unsigned a, unsigned b, float c) {
  float d;
  asm("v_dot2_f32_bf16 %0, %1, %2, %3" : "=v"(d) : "v"(a), "v"(b), "v"(c));
  return d;
}
// 16-wide bf16 dot: two uint4 slots (k 0..7, 8..15) against cepk[0..7]
__device__ __forceinline__ float tdot(uint4 a, uint4 b, const unsigned* cp) {
  float s = 0.f;
  s = dot2bf(a.x, cp[0], s); s = dot2bf(a.y, cp[1], s);
  s = dot2bf(a.z, cp[2], s); s = dot2bf(a.w, cp[3], s);
  s = dot2bf(b.x, cp[4], s); s = dot2bf(b.y, cp[5], s);
  s = dot2bf(b.z, cp[6], s); s = dot2bf(b.w, cp[7], s);
  return s;
}

// t-build + banded matvec partials for d in [D0, D0+ND)
template<int D0, int ND>
__device__ __forceinline__ void tmv_part(const uint4* m4u, const unsigned* cepk,
                                         const float* stat, int ii, int b, int swz,
                                         float rv[5]) {
  #pragma unroll
  for (int dd = 0; dd < ND; ++dd) {
    const int d = D0 + dd;
    const int ba = (0*7 + d)*120 + ii*2;
    const int bb = (1*7 + d)*120 + ii*2;
    const int bc = (2*7 + d)*120 + ii*2;
    const int bd = (3*7 + d)*120 + ii*2;
    const uint4 xa = m4u[ba + swz], ya = m4u[ba + 1 - swz];
    const uint4 xb = m4u[bb + swz], yb = m4u[bb + 1 - swz];
    const uint4 xc = m4u[bc + swz], yc = m4u[bc + 1 - swz];
    const uint4 xd = m4u[bd + swz], yd = m4u[bd + 1 - swz];
    const float a11 = tdot(xa, ya, cepk);
    const float a12 = tdot(xb, yb, cepk);
    const float a21 = tdot(xc, yc, cepk);
    const float a22 = tdot(xd, yd, cepk);
    const int si = (ii + d)*4 + b;
    const float mun  = stat[si];
    const float mln  = stat[288  + si];
    const float pcun = stat[576  + si];
    const float pcsn = stat[864  + si];
    const float pcln = stat[1152 + si];
    rv[0] += a11*mun + a12*mln;
    rv[1] += a21*mun + a22*mln;
    rv[2] += a11*a11*pcun + 2.f*a11*a12*pcsn + a12*a12*pcln;
    rv[3] += a21*a21*pcun + 2.f*a21*a22*pcsn + a22*a22*pcln;
    rv[4] += a21*a11*pcun + (a22*a11 + a21*a12)*pcsn + a22*a12*pcln;
  }
}

// ---------------- pre-pass: ctrl = relu(act@w1+b1)@w2 + b2 -> o4 region ----
// grid 4096 x 256 (4 waves); wave handles bt = blockIdx*4+w + it*16384,
// register double-buffer prefetch of act. w2 tiled lane-major.
__launch_bounds__(256, 4)
__global__ void ctrl_pre(const float* __restrict__ actp,  // (B*T,10)
                         const float* __restrict__ w1,    // (10,60)
                         const float* __restrict__ b1,    // (60)
                         const float* __restrict__ w2,    // (60,120)
                         const float* __restrict__ b2,    // (120)
                         float* __restrict__ out)
{
  __shared__ float w1s[640];                 // [a][j<64]
  __shared__ float b1s[64];
  __shared__ __align__(16) float w2pk[7680]; // [p][j4][lane][e] = w2[4j4+e][2*lane+p]
  __shared__ float b2s[128];
  __shared__ __align__(16) float hbuf[256];  // [w][j<64]

  const int tid = threadIdx.x;
  for (int idx = tid; idx < 640; idx += 256) {
    const int j = idx & 63, a = idx >> 6;
    w1s[idx] = (j < 60) ? w1[a*60 + j] : 0.f;
  }
  for (int idx = tid; idx < 7680; idx += 256) {
    const int e = idx & 3;
    const int l = (idx >> 2) & 63;
    const int rest = idx >> 8;
    const int j4 = rest % 15;
    const int p  = rest / 15;
    w2pk[idx] = (l < 60) ? w2[(4*j4 + e)*120 + 2*l + p] : 0.f;
  }
  if (tid < 64)  b1s[tid] = (tid < 60)  ? b1[tid] : 0.f;
  if (tid < 128) b2s[tid] = (tid < 120) ? b2[tid] : 0.f;
  __syncthreads();

  const int w = tid >> 6, lane = tid & 63;
  float* o4 = out + 46080000L;
  const float4* w2pk4 = (const float4*)w2pk;
  const float4* hb4   = (const float4*)hbuf;

  long bt = (long)(blockIdx.x*4 + w);
  float av = (lane < 10 && bt < 153600L) ? actp[bt*10 + lane] : 0.f;

  for (int it = 0; it < 10; ++it) {
    const long btn = bt + 16384L;
    const float avn = (lane < 10 && btn < 153600L) ? actp[btn*10 + lane] : 0.f;

    if (bt < 153600L) {
      float hj = b1s[lane];
      #pragma unroll
      for (int a = 0; a < 10; ++a) hj += __shfl(av, a) * w1s[a*64 + lane];
      hbuf[w*64 + lane] = (lane < 60) ? fmaxf(hj, 0.f) : 0.f;

      float s0 = 0.f, s1 = 0.f;
      if (lane < 60) { s0 = b2s[2*lane]; s1 = b2s[2*lane + 1]; }
      #pragma unroll
      for (int j4 = 0; j4 < 15; ++j4) {
        const float4 hq = hb4[w*16 + j4];
        s0 += dot4(hq, w2pk4[(0*15 + j4)*64 + lane]);
        s1 += dot4(hq, w2pk4[(1*15 + j4)*64 + lane]);
      }
      if (lane < 60) ((float2*)(o4 + bt*120))[lane] = make_float2(s0, s1);
    }
    bt = btn; av = avn;
  }
}

// ---------------- main scan kernel ----------------
// 1024 threads = 16 waves, 4/SIMD (one of each chunk per SIMD).
// chunk = w>>2: c0 front (Kalman/stat/logits) + t-build d{0,1} + carries;
//   c1: d{2,3}; c2: d{4,5}; c3: d{6} + o0..o3 (from stat) + o4..o7 (combine).
// lane=(r,b): iraw=(w&3)*16+r, b=lane&3. grid 256 -> B=1024. 2 barriers/step.
__launch_bounds__(1024, 4)
__global__ void acrkn(const float* __restrict__ lob,   // (B,T,60)
                      const float* __restrict__ ovr,   // (B,T,60)
                      const float* __restrict__ im,    // (B,120)
                      const float* __restrict__ icu,   // (B,60)
                      const float* __restrict__ icl,   // (B,60)
                      const float* __restrict__ ics,   // (B,60)
                      const float* __restrict__ tm11,  // (15,60,60)
                      const float* __restrict__ tm12,
                      const float* __restrict__ tm21,
                      const float* __restrict__ tm22,
                      const float* __restrict__ cw,    // (120,15)
                      const float* __restrict__ cb,    // (15)
                      const float* __restrict__ ltc,   // (120)
                      float* __restrict__ out)
{
  // basis packed bf16x2; uint4 slot index (mat*7+d)*120 + i*2 + sp, sp=s^((i>>2)&1)
  __shared__ __align__(16) unsigned m4b[13440];   // 53760 B
  __shared__ __align__(16) float cwc[2048];       // logits weights (f4 = c*128+p)
  __shared__ __align__(16) float stat[1440];      // [vec][row 0..71][b]
  __shared__ __align__(16) float pscratch[4096];  // [wq][lane][k16] lane-major
  __shared__ __align__(16) float parts[256];      // [wq][b][k16]
  __shared__ __align__(16) float red[5120];       // [chunk][v][i<64][b]
  __shared__ float cbs[16];

  const int tid = threadIdx.x;

  // ---------------- one-time LDS staging ----------------
  for (int idx = tid; idx < 13440; idx += 1024) {
    const int c2 = idx & 7;
    int rest = idx >> 3;
    const int i = rest % 60;  rest /= 60;
    const int d = rest % 7;
    const int mat = rest / 7;
    const int k0 = 2*c2;
    const int j = i + d - 3;
    const float* tp = (mat == 0) ? tm11 : (mat == 1) ? tm12 : (mat == 2) ? tm21 : tm22;
    float ve = 0.f, vo = 0.f;
    if (j >= 0 && j < 60) {
      ve = tp[(k0*60 + i)*60 + j];
      if (k0 + 1 < 15) vo = tp[((k0+1)*60 + i)*60 + j];
    }
    const unsigned u = ((unsigned)bf16bits(vo) << 16) | (unsigned)bf16bits(ve);
    const int s = c2 >> 2, q = c2 & 3;
    const int sp = s ^ ((i >> 2) & 1);
    m4b[(((mat*7 + d)*60 + i)*2 + sp)*4 + q] = u;
  }
  if (tid < 512) {
    const int f4 = tid;
    const int p = f4 & 127, c = f4 >> 7;
    const int col = (p < 60) ? p : ((p >= 64 && p < 124) ? (p - 4) : -1);
    float v0 = 0.f, v1 = 0.f, v2 = 0.f, v3 = 0.f;
    if (col >= 0) {
      const int k0 = c*4;
      v0 = cw[col*15 + k0+0];
      v1 = cw[col*15 + k0+1];
      v2 = cw[col*15 + k0+2];
      v3 = (k0+3 < 15) ? cw[col*15 + k0+3] : 0.f;
    }
    ((float4*)cwc)[f4] = make_float4(v0, v1, v2, v3);
  }
  for (int idx = tid; idx < 1440; idx += 1024) stat[idx] = 0.f;
  if (tid < 16) cbs[tid] = (tid < 15) ? cb[tid] : 0.f;

  const int w = tid >> 6;
  const int chunk = w >> 2;        // 0 front | 1 d23 | 2 d45 | 3 d6+stores
  const int wq = w & 3;
  const int lane = tid & 63;
  const int r = lane >> 2;
  const int b = lane & 3;
  const int iraw = wq*16 + r;
  const bool valid = (iraw < 60);
  const int ii = valid ? iraw : 0;
  const int gb = blockIdx.x*4 + b;
  const int swz = (ii >> 2) & 1;

  // carries (front only reads them)
  float mu_c = 0.f, ml_c = 0.f, cu_c = 1.f, cl_c = 1.f, cs_c = 0.f;
  float tcu_r = 1.f, tcl_r = 1.f;
  if (valid) {
    mu_c = im[gb*120 + ii];
    ml_c = im[gb*120 + 60 + ii];
    cu_c = icu[gb*60 + ii];
    cl_c = icl[gb*60 + ii];
    cs_c = ics[gb*60 + ii];
    const float l0 = ltc[ii], l1 = ltc[60 + ii];
    tcu_r = (l0 >= 0.f) ? l0 + 1.f : __expf(l0);   // elup1
    tcl_r = (l1 >= 0.f) ? l1 + 1.f : __expf(l1);
  }

  const uint4*  m4u    = (const uint4*)m4b;
  const float4* cwc4   = (const float4*)cwc;
  const float4* parts4 = (const float4*)parts;
  float4*       ps4    = (float4*)pscratch;

  float* o0 = out;                 // post_means  (B,T,120)
  float* o1 = out + 18432000L;     // pcu (B,T,60)
  float* o2 = out + 27648000L;     // pcl
  float* o3 = out + 36864000L;     // pcs
  float* o4 = out + 46080000L;     // prior_means (ctrl until overwritten)
  float* o5 = out + 64512000L;     // ncu
  float* o6 = out + 73728000L;     // ncl
  float* o7 = out + 82944000L;     // ncs

  __syncthreads();

  for (int t = 0; t < TT; ++t) {
    const long ob120 = ((long)gb*TT + t)*120;

    // ---- ctrl loads (chunks 0 and 3 only; pre-B1, barrier-ordered vs o4 store) ----
    float ctrl_u = 0.f, ctrl_l = 0.f;
    if ((chunk == 0 || chunk == 3) && valid) {
      ctrl_u = o4[ob120 + ii];
      ctrl_l = o4[ob120 + 60 + ii];
    }

    // ---- phase A (front only): Kalman + stat + logits + LDS-transpose reduce ----
    if (chunk == 0) {
      const long ib = (long)gb*(TT*60) + t*60 + ii;
      float obs = 0.f, ovv = 1.f;
      if (valid) { obs = lob[ib]; ovv = ovr[ib]; }
      const float denom = cu_c + ovv;
      const float inv = 1.0f / denom;
      const float qu = cu_c * inv;
      const float ql = cs_c * inv;
      const float res = obs - mu_c;
      float pm_u = mu_c + qu*res;
      float pm_l = ml_c + ql*res;
      const float f1 = 1.f - qu;
      float pcu = f1*cu_c, pcs = f1*cs_c, pcl = cl_c - ql*cs_c;
      if (!valid) { pm_u = 0.f; pm_l = 0.f; pcu = 0.f; pcs = 0.f; pcl = 0.f; }

      if (valid) {
        stat[(0*72 + ii + 3)*4 + b] = pm_u;
        stat[(1*72 + ii + 3)*4 + b] = pm_l;
        stat[(2*72 + ii + 3)*4 + b] = pcu;
        stat[(3*72 + ii + 3)*4 + b] = pcs;
        stat[(4*72 + ii + 3)*4 + b] = pcl;
      }

      // logit partials (invalid lanes contribute exact zeros: pm=0)
      float p[16];
      #pragma unroll
      for (int k = 0; k < 16; ++k) p[k] = 0.f;
      #pragma unroll
      for (int c = 0; c < 4; ++c) {
        const float4 wu = cwc4[c*128 + ii];
        const float4 wl = cwc4[c*128 + 64 + ii];
        p[c*4+0] += pm_u*wu.x + pm_l*wl.x;
        p[c*4+1] += pm_u*wu.y + pm_l*wl.y;
        p[c*4+2] += pm_u*wu.z + pm_l*wl.z;
        p[c*4+3] += pm_u*wu.w + pm_l*wl.w;
      }
      // lane-major scratch write (contiguous 64B per lane), then column-sum k=r
      const int pb = (wq*64 + lane)*4;
      ps4[pb+0] = make_float4(p[0],  p[1],  p[2],  p[3]);
      ps4[pb+1] = make_float4(p[4],  p[5],  p[6],  p[7]);
      ps4[pb+2] = make_float4(p[8],  p[9],  p[10], p[11]);
      ps4[pb+3] = make_float4(p[12], p[13], p[14], p[15]);
      const int rbase = wq*1024 + b*16 + r;
      float tv[16];
      #pragma unroll
      for (int rp = 0; rp < 16; ++rp) tv[rp] = pscratch[rbase + rp*64];
      const float s0 = (tv[0]+tv[1]) + (tv[2]+tv[3]);
      const float s1 = (tv[4]+tv[5]) + (tv[6]+tv[7]);
      const float s2 = (tv[8]+tv[9]) + (tv[10]+tv[11]);
      const float s3 = (tv[12]+tv[13]) + (tv[14]+tv[15]);
      parts[(wq*4 + b)*16 + r] = (s0+s1) + (s2+s3);
    }
    __syncthreads();   // B1

    // ---- c3: store post_means/post_covs from stat ----
    if (chunk == 3 && valid) {
      const long ob60 = ((long)gb*TT + t)*60;
      const float s_pmu = stat[(0*72 + ii + 3)*4 + b];
      const float s_pml = stat[(1*72 + ii + 3)*4 + b];
      const float s_pcu = stat[(2*72 + ii + 3)*4 + b];
      const float s_pcs = stat[(3*72 + ii + 3)*4 + b];
      const float s_pcl = stat[(4*72 + ii + 3)*4 + b];
      o0[ob120 + ii]      = s_pmu;
      o0[ob120 + 60 + ii] = s_pml;
      o1[ob60 + ii] = s_pcu;
      o2[ob60 + ii] = s_pcl;
      o3[ob60 + ii] = s_pcs;
    }

    // ---- softmax (all waves, redundant per b; no max-sub: |logits| ~ <=4) ----
    float q[16];
    #pragma unroll
    for (int k = 0; k < 16; ++k) q[k] = cbs[k];
    #pragma unroll
    for (int ww = 0; ww < 4; ++ww) {
      #pragma unroll
      for (int c = 0; c < 4; ++c) {
        const float4 pv = parts4[(ww*4 + b)*4 + c];
        q[4*c+0] += pv.x; q[4*c+1] += pv.y; q[4*c+2] += pv.z; q[4*c+3] += pv.w;
      }
    }
    float ce[16];
    #pragma unroll
    for (int k = 0; k < 15; ++k) ce[k] = __expf(q[k]);
    const float e0 = (ce[0]+ce[1]) + (ce[2]+ce[3]);
    const float e1 = (ce[4]+ce[5]) + (ce[6]+ce[7]);
    const float e2 = (ce[8]+ce[9]) + (ce[10]+ce[11]);
    const float e3 = (ce[12]+ce[13]) + ce[14];
    const float rs = 1.f / ((e0+e1) + (e2+e3));
    #pragma unroll
    for (int k = 0; k < 15; ++k) ce[k] *= rs;
    ce[15] = 0.f;
    unsigned cepk[8];
    #pragma unroll
    for (int j = 0; j < 8; ++j)
      cepk[j] = ((unsigned)bf16bits(ce[2*j+1]) << 16) | (unsigned)bf16bits(ce[2*j]);

    // ---- t-build + matvec partials, d-range per chunk ----
    float rv[5] = {0.f, 0.f, 0.f, 0.f, 0.f};
    if      (chunk == 0) tmv_part<0, 2>(m4u, cepk, stat, ii, b, swz, rv);
    else if (chunk == 1) tmv_part<2, 2>(m4u, cepk, stat, ii, b, swz, rv);
    else if (chunk == 2) tmv_part<4, 2>(m4u, cepk, stat, ii, b, swz, rv);
    else                 tmv_part<6, 1>(m4u, cepk, stat, ii, b, swz, rv);

    if (valid) {
      #pragma unroll
      for (int v = 0; v < 5; ++v) red[chunk*1280 + v*256 + ii*4 + b] = rv[v];
    }
    __syncthreads();   // B2

    // ---- combine (front: carries; c3: stores o4..o7) ----
    if (chunk == 0 || chunk == 3) {
      const int rb = ii*4 + b;
      float nmu = ctrl_u, nml = ctrl_l, ncu = tcu_r, ncl = tcl_r, ncs = 0.f;
      #pragma unroll
      for (int c = 0; c < 4; ++c) {
        nmu += red[c*1280 + 0*256 + rb];
        nml += red[c*1280 + 1*256 + rb];
        ncu += red[c*1280 + 2*256 + rb];
        ncl += red[c*1280 + 3*256 + rb];
        ncs += red[c*1280 + 4*256 + rb];
      }
      if (chunk == 3) {
        if (valid) {
          const long ob60 = ((long)gb*TT + t)*60;
          o4[ob120 + ii]      = nmu;   // overwrite ctrl with prior_means
          o4[ob120 + 60 + ii] = nml;
          o5[ob60 + ii] = ncu;
          o6[ob60 + ii] = ncl;
          o7[ob60 + ii] = ncs;
        }
      } else {
        mu_c = nmu; ml_c = nml; cu_c = ncu; cl_c = ncl; cs_c = ncs;
      }
    }
    // no third barrier: next-step stat/parts/pscratch writes (front, post-B2)
    // precede B1(t+1); red(t+1) writes happen post-B1(t+1), after these reads.
  }
}

} // namespace

extern "C" void kernel_launch(void* const* d_in, const int* in_sizes, int n_in,
                              void* d_out, int out_size, void* d_ws, size_t ws_size,
                              hipStream_t stream) {
  (void)in_sizes; (void)n_in; (void)d_ws; (void)ws_size; (void)out_size;
  const float* lob  = (const float*)d_in[0];
  const float* ovr  = (const float*)d_in[1];
  const float* actp = (const float*)d_in[2];
  const float* im   = (const float*)d_in[3];
  const float* icu  = (const float*)d_in[4];
  const float* icl  = (const float*)d_in[5];
  const float* ics  = (const float*)d_in[6];
  const float* tm11 = (const float*)d_in[7];
  const float* tm12 = (const float*)d_in[8];
  const float* tm21 = (const float*)d_in[9];
  const float* tm22 = (const float*)d_in[10];
  const float* cw   = (const float*)d_in[11];
  const float* cb   = (const float*)d_in[12];
  const float* w1   = (const float*)d_in[13];
  const float* b1   = (const float*)d_in[14];
  const float* w2   = (const float*)d_in[15];
  const float* b2   = (const float*)d_in[16];
  const float* ltc  = (const float*)d_in[17];

  ctrl_pre<<<dim3(4096), dim3(256), 0, stream>>>(actp, w1, b1, w2, b2, (float*)d_out);
  acrkn<<<dim3(256), dim3(1024), 0, stream>>>(
      lob, ovr, im, icu, icl, ics,
      tm11, tm12, tm21, tm22, cw, cb, ltc,
      (float*)d_out);
}

// Round 8
// 627.493 us; speedup vs baseline: 1.5407x; 1.1557x over previous
//
#include <hip/hip_runtime.h>
#include <hip/hip_bf16.h>

namespace {

constexpr int TT = 150;

__device__ __forceinline__ float dot4(float4 a, float4 b) {
  return a.x*b.x + a.y*b.y + a.z*b.z + a.w*b.w;
}
__device__ __forceinline__ unsigned short bf16bits(float v) {
  __hip_bfloat16 h = __float2bfloat16(v);
  return *reinterpret_cast<unsigned short*>(&h);
}
// f32 += dot of a bf16 pair (packed u32) with a bf16 pair (packed u32)
__device__ __forceinline__ float dot2bf(unsigned a, unsigned b, float c) {
  float d;
  asm("v_dot2_f32_bf16 %0, %1, %2, %3" : "=v"(d) : "v"(a), "v"(b), "v"(c));
  return d;
}
// 16-wide bf16 dot: two uint4 slots (k 0..7, 8..15) against cepk[0..7]
__device__ __forceinline__ float tdot(uint4 a, uint4 b, const unsigned* cp) {
  float s = 0.f;
  s = dot2bf(a.x, cp[0], s); s = dot2bf(a.y, cp[1], s);
  s = dot2bf(a.z, cp[2], s); s = dot2bf(a.w, cp[3], s);
  s = dot2bf(b.x, cp[4], s); s = dot2bf(b.y, cp[5], s);
  s = dot2bf(b.z, cp[6], s); s = dot2bf(b.w, cp[7], s);
  return s;
}

// t-build + banded matvec partials for d in [D0, D0+ND)
template<int D0, int ND>
__device__ __forceinline__ void tmv_part(const uint4* m4u, const unsigned* cepk,
                                         const float* stat, int ii, int b, int swz,
                                         float rv[5]) {
  #pragma unroll
  for (int dd = 0; dd < ND; ++dd) {
    const int d = D0 + dd;
    const int ba = (0*7 + d)*120 + ii*2;
    const int bb = (1*7 + d)*120 + ii*2;
    const int bc = (2*7 + d)*120 + ii*2;
    const int bd = (3*7 + d)*120 + ii*2;
    const uint4 xa = m4u[ba + swz], ya = m4u[ba + 1 - swz];
    const uint4 xb = m4u[bb + swz], yb = m4u[bb + 1 - swz];
    const uint4 xc = m4u[bc + swz], yc = m4u[bc + 1 - swz];
    const uint4 xd = m4u[bd + swz], yd = m4u[bd + 1 - swz];
    const float a11 = tdot(xa, ya, cepk);
    const float a12 = tdot(xb, yb, cepk);
    const float a21 = tdot(xc, yc, cepk);
    const float a22 = tdot(xd, yd, cepk);
    const int si = (ii + d)*4 + b;
    const float mun  = stat[si];
    const float mln  = stat[288  + si];
    const float pcun = stat[576  + si];
    const float pcsn = stat[864  + si];
    const float pcln = stat[1152 + si];
    rv[0] += a11*mun + a12*mln;
    rv[1] += a21*mun + a22*mln;
    rv[2] += a11*a11*pcun + 2.f*a11*a12*pcsn + a12*a12*pcln;
    rv[3] += a21*a21*pcun + 2.f*a21*a22*pcsn + a22*a22*pcln;
    rv[4] += a21*a11*pcun + (a22*a11 + a21*a12)*pcsn + a22*a12*pcln;
  }
}

// ---------------- single fused kernel ----------------
// 1024 threads = 16 waves, 4/SIMD. chunk = w>>2:
//   c0: front (Kalman/stat/logits) + t-build d{0,1} + carries
//   c1: ctrl cols 0..59 (phase A) + t-build d{2,3}
//   c2: ctrl cols 60..119 (phase A) + t-build d{4,5}
//   c3: t-build d{6} + all global stores
// lane=(r,b) for (r,b)-mapped phases: iraw=(w&3)*16+r, b=lane&3.
// ctrl phase uses lane=j/col, wave wq = batch slot. grid 256 -> B=1024.
__launch_bounds__(1024, 4)
__global__ void acrkn(const float* __restrict__ lob,   // (B,T,60)
                      const float* __restrict__ ovr,   // (B,T,60)
                      const float* __restrict__ actp,  // (B,T,10)
                      const float* __restrict__ im,    // (B,120)
                      const float* __restrict__ icu,   // (B,60)
                      const float* __restrict__ icl,   // (B,60)
                      const float* __restrict__ ics,   // (B,60)
                      const float* __restrict__ tm11,  // (15,60,60)
                      const float* __restrict__ tm12,
                      const float* __restrict__ tm21,
                      const float* __restrict__ tm22,
                      const float* __restrict__ cw,    // (120,15)
                      const float* __restrict__ cb,    // (15)
                      const float* __restrict__ w1,    // (10,60)
                      const float* __restrict__ b1,    // (60)
                      const float* __restrict__ w2,    // (60,120)
                      const float* __restrict__ b2,    // (120)
                      const float* __restrict__ ltc,   // (120)
                      float* __restrict__ out)
{
  // basis packed bf16x2; uint4 slot index (mat*7+d)*120 + i*2 + sp, sp=s^((i>>2)&1)
  __shared__ __align__(16) unsigned m4b[13440];   // 53760 B
  __shared__ __align__(16) float cwc[2048];       // logits weights (f4 = c*128+p)
  __shared__ __align__(16) float stat[1440];      // [vec][row 0..71][b]
  __shared__ __align__(16) float pscratch[5120];  // [wq][lane][20] padded lane-major
  __shared__ __align__(16) float parts[256];      // [wq][b][k16]
  __shared__ __align__(16) float red[5120];       // [chunk][v][i<64][b]
  __shared__ __align__(16) float ctl[1024];       // [par][b][128] ctrl cols
  __shared__ __align__(16) float hctl[512];       // [w-4 (0..7)][j<64]
  __shared__ __align__(16) float w2T[7680];       // [col<128][j4<15][e] = w2[4j4+e][col]
  __shared__ float w1s[640];                      // [a][j<64]
  __shared__ float b1s[64];
  __shared__ float b2s[128];
  __shared__ float cbs[16];

  const int tid = threadIdx.x;

  // ---------------- one-time LDS staging ----------------
  for (int idx = tid; idx < 13440; idx += 1024) {
    const int c2 = idx & 7;
    int rest = idx >> 3;
    const int i = rest % 60;  rest /= 60;
    const int d = rest % 7;
    const int mat = rest / 7;
    const int k0 = 2*c2;
    const int j = i + d - 3;
    const float* tp = (mat == 0) ? tm11 : (mat == 1) ? tm12 : (mat == 2) ? tm21 : tm22;
    float ve = 0.f, vo = 0.f;
    if (j >= 0 && j < 60) {
      ve = tp[(k0*60 + i)*60 + j];
      if (k0 + 1 < 15) vo = tp[((k0+1)*60 + i)*60 + j];
    }
    const unsigned u = ((unsigned)bf16bits(vo) << 16) | (unsigned)bf16bits(ve);
    const int s = c2 >> 2, q = c2 & 3;
    const int sp = s ^ ((i >> 2) & 1);
    m4b[(((mat*7 + d)*60 + i)*2 + sp)*4 + q] = u;
  }
  if (tid < 512) {
    const int f4 = tid;
    const int p = f4 & 127, c = f4 >> 7;
    const int col = (p < 60) ? p : ((p >= 64 && p < 124) ? (p - 4) : -1);
    float v0 = 0.f, v1 = 0.f, v2 = 0.f, v3 = 0.f;
    if (col >= 0) {
      const int k0 = c*4;
      v0 = cw[col*15 + k0+0];
      v1 = cw[col*15 + k0+1];
      v2 = cw[col*15 + k0+2];
      v3 = (k0+3 < 15) ? cw[col*15 + k0+3] : 0.f;
    }
    ((float4*)cwc)[f4] = make_float4(v0, v1, v2, v3);
  }
  for (int idx = tid; idx < 7680; idx += 1024) {
    const int e = idx & 3;
    const int f4 = idx >> 2;
    const int j4 = f4 % 15;
    const int col = f4 / 15;
    const int j = 4*j4 + e;
    w2T[idx] = (j < 60 && col < 120) ? w2[j*120 + col] : 0.f;   // idx = col*60+j4*4+e
  }
  for (int idx = tid; idx < 640; idx += 1024) {
    const int j = idx & 63, a = idx >> 6;
    w1s[idx] = (j < 60) ? w1[a*60 + j] : 0.f;
  }
  for (int idx = tid; idx < 1440; idx += 1024) stat[idx] = 0.f;
  if (tid < 64)  b1s[tid] = (tid < 60)  ? b1[tid] : 0.f;
  if (tid < 128) b2s[tid] = (tid < 120) ? b2[tid] : 0.f;
  if (tid < 16)  cbs[tid] = (tid < 15)  ? cb[tid] : 0.f;

  const int w = tid >> 6;
  const int chunk = w >> 2;        // 0 front+d01 | 1 ctrl+d23 | 2 ctrl+d45 | 3 d6+stores
  const int wq = w & 3;
  const int lane = tid & 63;
  const int r = lane >> 2;
  const int b = lane & 3;
  const int iraw = wq*16 + r;
  const bool valid = (iraw < 60);
  const int ii = valid ? iraw : 0;
  const int gb = blockIdx.x*4 + b;
  const int swz = (ii >> 2) & 1;

  // carries (front only reads them)
  float mu_c = 0.f, ml_c = 0.f, cu_c = 1.f, cl_c = 1.f, cs_c = 0.f;
  float tcu_r = 1.f, tcl_r = 1.f;
  if (valid) {
    mu_c = im[gb*120 + ii];
    ml_c = im[gb*120 + 60 + ii];
    cu_c = icu[gb*60 + ii];
    cl_c = icl[gb*60 + ii];
    cs_c = ics[gb*60 + ii];
    const float l0 = ltc[ii], l1 = ltc[60 + ii];
    tcu_r = (l0 >= 0.f) ? l0 + 1.f : __expf(l0);   // elup1
    tcl_r = (l1 >= 0.f) ? l1 + 1.f : __expf(l1);
  }

  const uint4*  m4u    = (const uint4*)m4b;
  const float4* cwc4   = (const float4*)cwc;
  const float4* parts4 = (const float4*)parts;
  float4*       ps4    = (float4*)pscratch;

  float* o0 = out;                 // post_means  (B,T,120)
  float* o1 = out + 18432000L;     // pcu (B,T,60)
  float* o2 = out + 27648000L;     // pcl
  float* o3 = out + 36864000L;     // pcs
  float* o4 = out + 46080000L;     // prior_means (B,T,120)
  float* o5 = out + 64512000L;     // ncu
  float* o6 = out + 73728000L;     // ncl
  float* o7 = out + 82944000L;     // ncs

  __syncthreads();

  for (int t = 0; t < TT; ++t) {
    const long ob120 = ((long)gb*TT + t)*120;

    // ---- phase A ----
    if (chunk == 0) {
      // front: Kalman + stat + logits partials + padded-transpose reduce
      const long ib = (long)gb*(TT*60) + t*60 + ii;
      float obs = 0.f, ovv = 1.f;
      if (valid) { obs = lob[ib]; ovv = ovr[ib]; }
      const float denom = cu_c + ovv;
      const float inv = 1.0f / denom;
      const float qu = cu_c * inv;
      const float ql = cs_c * inv;
      const float res = obs - mu_c;
      float pm_u = mu_c + qu*res;
      float pm_l = ml_c + ql*res;
      const float f1 = 1.f - qu;
      float pcu = f1*cu_c, pcs = f1*cs_c, pcl = cl_c - ql*cs_c;
      if (!valid) { pm_u = 0.f; pm_l = 0.f; pcu = 0.f; pcs = 0.f; pcl = 0.f; }

      if (valid) {
        stat[(0*72 + ii + 3)*4 + b] = pm_u;
        stat[(1*72 + ii + 3)*4 + b] = pm_l;
        stat[(2*72 + ii + 3)*4 + b] = pcu;
        stat[(3*72 + ii + 3)*4 + b] = pcs;
        stat[(4*72 + ii + 3)*4 + b] = pcl;
      }

      float p[16];
      #pragma unroll
      for (int k = 0; k < 16; ++k) p[k] = 0.f;
      #pragma unroll
      for (int c = 0; c < 4; ++c) {
        const float4 wu = cwc4[c*128 + ii];
        const float4 wl = cwc4[c*128 + 64 + ii];
        p[c*4+0] += pm_u*wu.x + pm_l*wl.x;
        p[c*4+1] += pm_u*wu.y + pm_l*wl.y;
        p[c*4+2] += pm_u*wu.z + pm_l*wl.z;
        p[c*4+3] += pm_u*wu.w + pm_l*wl.w;
      }
      // padded lane-major scratch (stride 20 floats = 80B -> 8 words/bank ideal)
      const int pb = (wq*64 + lane)*5;
      ps4[pb+0] = make_float4(p[0],  p[1],  p[2],  p[3]);
      ps4[pb+1] = make_float4(p[4],  p[5],  p[6],  p[7]);
      ps4[pb+2] = make_float4(p[8],  p[9],  p[10], p[11]);
      ps4[pb+3] = make_float4(p[12], p[13], p[14], p[15]);
      float tv[16];
      #pragma unroll
      for (int rp = 0; rp < 16; ++rp) tv[rp] = pscratch[(wq*64 + 4*rp + b)*20 + r];
      const float s0 = (tv[0]+tv[1]) + (tv[2]+tv[3]);
      const float s1 = (tv[4]+tv[5]) + (tv[6]+tv[7]);
      const float s2 = (tv[8]+tv[9]) + (tv[10]+tv[11]);
      const float s3 = (tv[12]+tv[13]) + (tv[14]+tv[15]);
      parts[(wq*4 + b)*16 + r] = (s0+s1) + (s2+s3);
    } else if (chunk == 1 || chunk == 2) {
      // ctrl MLP for batch slot wq, this chunk's column half; lane = j / col
      const int gbc = blockIdx.x*4 + wq;
      const float av = (lane < 10) ? actp[((long)gbc*TT + t)*10 + lane] : 0.f;
      float hj = b1s[lane];
      #pragma unroll
      for (int a = 0; a < 10; ++a) hj += __shfl(av, a) * w1s[a*64 + lane];
      const int hw = w - 4;               // 0..7
      hctl[hw*64 + lane] = (lane < 60) ? fmaxf(hj, 0.f) : 0.f;
      const int col = (chunk == 1) ? lane : 60 + lane;
      float s = (lane < 60) ? b2s[col] : 0.f;
      const float4* hb4c = (const float4*)&hctl[hw*64];
      #pragma unroll
      for (int j4 = 0; j4 < 15; ++j4)
        s += dot4(hb4c[j4], *(const float4*)&w2T[col*60 + j4*4]);
      if (lane < 60) ctl[(t&1)*512 + wq*128 + col] = s;
    }
    // c3 idle in phase A
    __syncthreads();   // B1

    // ---- c3: store post_means/post_covs from stat ----
    if (chunk == 3 && valid) {
      const long ob60 = ((long)gb*TT + t)*60;
      const float s_pmu = stat[(0*72 + ii + 3)*4 + b];
      const float s_pml = stat[(1*72 + ii + 3)*4 + b];
      const float s_pcu = stat[(2*72 + ii + 3)*4 + b];
      const float s_pcs = stat[(3*72 + ii + 3)*4 + b];
      const float s_pcl = stat[(4*72 + ii + 3)*4 + b];
      o0[ob120 + ii]      = s_pmu;
      o0[ob120 + 60 + ii] = s_pml;
      o1[ob60 + ii] = s_pcu;
      o2[ob60 + ii] = s_pcl;
      o3[ob60 + ii] = s_pcs;
    }

    // ---- softmax (all waves, redundant per b; no max-sub: |logits| small) ----
    float q[16];
    #pragma unroll
    for (int k = 0; k < 16; ++k) q[k] = cbs[k];
    #pragma unroll
    for (int ww = 0; ww < 4; ++ww) {
      #pragma unroll
      for (int c = 0; c < 4; ++c) {
        const float4 pv = parts4[(ww*4 + b)*4 + c];
        q[4*c+0] += pv.x; q[4*c+1] += pv.y; q[4*c+2] += pv.z; q[4*c+3] += pv.w;
      }
    }
    float ce[16];
    #pragma unroll
    for (int k = 0; k < 15; ++k) ce[k] = __expf(q[k]);
    const float e0 = (ce[0]+ce[1]) + (ce[2]+ce[3]);
    const float e1 = (ce[4]+ce[5]) + (ce[6]+ce[7]);
    const float e2 = (ce[8]+ce[9]) + (ce[10]+ce[11]);
    const float e3 = (ce[12]+ce[13]) + ce[14];
    const float rs = 1.f / ((e0+e1) + (e2+e3));
    #pragma unroll
    for (int k = 0; k < 15; ++k) ce[k] *= rs;
    ce[15] = 0.f;
    unsigned cepk[8];
    #pragma unroll
    for (int j = 0; j < 8; ++j)
      cepk[j] = ((unsigned)bf16bits(ce[2*j+1]) << 16) | (unsigned)bf16bits(ce[2*j]);

    // ---- t-build + matvec partials, d-range per chunk ----
    float rv[5] = {0.f, 0.f, 0.f, 0.f, 0.f};
    if      (chunk == 0) tmv_part<0, 2>(m4u, cepk, stat, ii, b, swz, rv);
    else if (chunk == 1) tmv_part<2, 2>(m4u, cepk, stat, ii, b, swz, rv);
    else if (chunk == 2) tmv_part<4, 2>(m4u, cepk, stat, ii, b, swz, rv);
    else                 tmv_part<6, 1>(m4u, cepk, stat, ii, b, swz, rv);

    if (valid) {
      #pragma unroll
      for (int v = 0; v < 5; ++v) red[chunk*1280 + v*256 + ii*4 + b] = rv[v];
    }
    __syncthreads();   // B2

    // ---- combine (front: carries; c3: stores o4..o7) ----
    if (chunk == 0 || chunk == 3) {
      const float ctrl_u = ctl[(t&1)*512 + b*128 + ii];
      const float ctrl_l = ctl[(t&1)*512 + b*128 + 60 + ii];
      const int rb = ii*4 + b;
      float nmu = ctrl_u, nml = ctrl_l, ncu = tcu_r, ncl = tcl_r, ncs = 0.f;
      #pragma unroll
      for (int c = 0; c < 4; ++c) {
        nmu += red[c*1280 + 0*256 + rb];
        nml += red[c*1280 + 1*256 + rb];
        ncu += red[c*1280 + 2*256 + rb];
        ncl += red[c*1280 + 3*256 + rb];
        ncs += red[c*1280 + 4*256 + rb];
      }
      if (chunk == 3) {
        if (valid) {
          const long ob60 = ((long)gb*TT + t)*60;
          o4[ob120 + ii]      = nmu;
          o4[ob120 + 60 + ii] = nml;
          o5[ob60 + ii] = ncu;
          o6[ob60 + ii] = ncl;
          o7[ob60 + ii] = ncs;
        }
      } else {
        mu_c = nmu; ml_c = nml; cu_c = ncu; cl_c = ncl; cs_c = ncs;
      }
    }
    // race notes: ctl is parity-double-buffered (write t+2 is after B2(t+1) >
    // all reads(t)); stat/parts/pscratch(t+1) writes are post-B2(t) by the same
    // barrier argument as rounds 6-7; red(t+1) writes are post-B1(t+1), after
    // all combine reads(t) which precede B1(t+1).
  }
}

} // namespace

extern "C" void kernel_launch(void* const* d_in, const int* in_sizes, int n_in,
                              void* d_out, int out_size, void* d_ws, size_t ws_size,
                              hipStream_t stream) {
  (void)in_sizes; (void)n_in; (void)d_ws; (void)ws_size; (void)out_size;
  const float* lob  = (const float*)d_in[0];
  const float* ovr  = (const float*)d_in[1];
  const float* actp = (const float*)d_in[2];
  const float* im   = (const float*)d_in[3];
  const float* icu  = (const float*)d_in[4];
  const float* icl  = (const float*)d_in[5];
  const float* ics  = (const float*)d_in[6];
  const float* tm11 = (const float*)d_in[7];
  const float* tm12 = (const float*)d_in[8];
  const float* tm21 = (const float*)d_in[9];
  const float* tm22 = (const float*)d_in[10];
  const float* cw   = (const float*)d_in[11];
  const float* cb   = (const float*)d_in[12];
  const float* w1   = (const float*)d_in[13];
  const float* b1   = (const float*)d_in[14];
  const float* w2   = (const float*)d_in[15];
  const float* b2   = (const float*)d_in[16];
  const float* ltc  = (const float*)d_in[17];

  acrkn<<<dim3(256), dim3(1024), 0, stream>>>(
      lob, ovr, actp, im, icu, icl, ics,
      tm11, tm12, tm21, tm22, cw, cb, w1, b1, w2, b2, ltc,
      (float*)d_out);
}

// Round 11
// 623.635 us; speedup vs baseline: 1.5503x; 1.0062x over previous
//
#include <hip/hip_runtime.h>
#include <hip/hip_bf16.h>

namespace {

constexpr int TT = 150;

__device__ __forceinline__ float dot4(float4 a, float4 b) {
  return a.x*b.x + a.y*b.y + a.z*b.z + a.w*b.w;
}
__device__ __forceinline__ unsigned short bf16bits(float v) {
  __hip_bfloat16 h = __float2bfloat16(v);
  return *reinterpret_cast<unsigned short*>(&h);
}
// f32 += dot of a bf16 pair (packed u32) with a bf16 pair (packed u32)
__device__ __forceinline__ float dot2bf(unsigned a, unsigned b, float c) {
  float d;
  asm("v_dot2_f32_bf16 %0, %1, %2, %3" : "=v"(d) : "v"(a), "v"(b), "v"(c));
  return d;
}
// 16-wide bf16 dot: two uint4 slots (k 0..7, 8..15) against cepk[0..7]
__device__ __forceinline__ float tdot(uint4 a, uint4 b, const unsigned* cp) {
  float s = 0.f;
  s = dot2bf(a.x, cp[0], s); s = dot2bf(a.y, cp[1], s);
  s = dot2bf(a.z, cp[2], s); s = dot2bf(a.w, cp[3], s);
  s = dot2bf(b.x, cp[4], s); s = dot2bf(b.y, cp[5], s);
  s = dot2bf(b.z, cp[6], s); s = dot2bf(b.w, cp[7], s);
  return s;
}

// t-build + banded matvec partials for d in [D0, D0+ND)
template<int D0, int ND>
__device__ __forceinline__ void tmv_part(const uint4* m4u, const unsigned* cepk,
                                         const float* stat, int ii, int b, int swz,
                                         float rv[5]) {
  #pragma unroll
  for (int dd = 0; dd < ND; ++dd) {
    const int d = D0 + dd;
    const int ba = (0*7 + d)*120 + ii*2;
    const int bb = (1*7 + d)*120 + ii*2;
    const int bc = (2*7 + d)*120 + ii*2;
    const int bd = (3*7 + d)*120 + ii*2;
    const uint4 xa = m4u[ba + swz], ya = m4u[ba + 1 - swz];
    const uint4 xb = m4u[bb + swz], yb = m4u[bb + 1 - swz];
    const uint4 xc = m4u[bc + swz], yc = m4u[bc + 1 - swz];
    const uint4 xd = m4u[bd + swz], yd = m4u[bd + 1 - swz];
    const float a11 = tdot(xa, ya, cepk);
    const float a12 = tdot(xb, yb, cepk);
    const float a21 = tdot(xc, yc, cepk);
    const float a22 = tdot(xd, yd, cepk);
    const int si = (ii + d)*4 + b;
    const float mun  = stat[si];
    const float mln  = stat[288  + si];
    const float pcun = stat[576  + si];
    const float pcsn = stat[864  + si];
    const float pcln = stat[1152 + si];
    rv[0] += a11*mun + a12*mln;
    rv[1] += a21*mun + a22*mln;
    rv[2] += a11*a11*pcun + 2.f*a11*a12*pcsn + a12*a12*pcln;
    rv[3] += a21*a21*pcun + 2.f*a21*a22*pcsn + a22*a22*pcln;
    rv[4] += a21*a11*pcun + (a22*a11 + a21*a12)*pcsn + a22*a12*pcln;
  }
}

// ---------------- single fused kernel (round-8 base + butterfly + ctl pad) ----
// 1024 threads = 16 waves, 4/SIMD. chunk = w>>2:
//   c0: front (Kalman/stat/logits) + t-build d{0,1} + carries
//   c1: ctrl cols 0..59 (phase A) + t-build d{2,3}
//   c2: ctrl cols 60..119 (phase A) + t-build d{4,5}
//   c3: o0..o3 stores (post-B1) + t-build d{6} + o4..o7 stores
// 2 barriers/step; softmax redundant per wave (round-8 structure, proven).
__launch_bounds__(1024, 4)
__global__ void acrkn(const float* __restrict__ lob,   // (B,T,60)
                      const float* __restrict__ ovr,   // (B,T,60)
                      const float* __restrict__ actp,  // (B,T,10)
                      const float* __restrict__ im,    // (B,120)
                      const float* __restrict__ icu,   // (B,60)
                      const float* __restrict__ icl,   // (B,60)
                      const float* __restrict__ ics,   // (B,60)
                      const float* __restrict__ tm11,  // (15,60,60)
                      const float* __restrict__ tm12,
                      const float* __restrict__ tm21,
                      const float* __restrict__ tm22,
                      const float* __restrict__ cw,    // (120,15)
                      const float* __restrict__ cb,    // (15)
                      const float* __restrict__ w1,    // (10,60)
                      const float* __restrict__ b1,    // (60)
                      const float* __restrict__ w2,    // (60,120)
                      const float* __restrict__ b2,    // (120)
                      const float* __restrict__ ltc,   // (120)
                      float* __restrict__ out)
{
  __shared__ __align__(16) unsigned m4b[13440];   // basis bf16x2 (53760 B)
  __shared__ __align__(16) float cwc[2048];       // logits weights (f4 = c*128+p)
  __shared__ __align__(16) float stat[1440];      // [vec][row 0..71][b]
  __shared__ __align__(16) float parts[256];      // [wq][b][k16]
  __shared__ __align__(16) float red[5120];       // [chunk][v][i<64][b]
  __shared__ __align__(16) float ctl[1056];       // [par][b][132] padded
  __shared__ __align__(16) float hctl[512];       // [w-4][j<64]
  __shared__ __align__(16) float w2T[7680];       // [col<128][j4<15][e]
  __shared__ float w1s[640];                      // [a][j<64]
  __shared__ float b1s[64];
  __shared__ float b2s[128];
  __shared__ float cbs[16];

  const int tid = threadIdx.x;

  // ---------------- one-time LDS staging ----------------
  for (int idx = tid; idx < 13440; idx += 1024) {
    const int c2 = idx & 7;
    int rest = idx >> 3;
    const int i = rest % 60;  rest /= 60;
    const int d = rest % 7;
    const int mat = rest / 7;
    const int k0 = 2*c2;
    const int j = i + d - 3;
    const float* tp = (mat == 0) ? tm11 : (mat == 1) ? tm12 : (mat == 2) ? tm21 : tm22;
    float ve = 0.f, vo = 0.f;
    if (j >= 0 && j < 60) {
      ve = tp[(k0*60 + i)*60 + j];
      if (k0 + 1 < 15) vo = tp[((k0+1)*60 + i)*60 + j];
    }
    const unsigned u = ((unsigned)bf16bits(vo) << 16) | (unsigned)bf16bits(ve);
    const int s = c2 >> 2, q = c2 & 3;
    const int sp = s ^ ((i >> 2) & 1);
    m4b[(((mat*7 + d)*60 + i)*2 + sp)*4 + q] = u;
  }
  if (tid < 512) {
    const int f4 = tid;
    const int p = f4 & 127, c = f4 >> 7;
    const int col = (p < 60) ? p : ((p >= 64 && p < 124) ? (p - 4) : -1);
    float v0 = 0.f, v1 = 0.f, v2 = 0.f, v3 = 0.f;
    if (col >= 0) {
      const int k0 = c*4;
      v0 = cw[col*15 + k0+0];
      v1 = cw[col*15 + k0+1];
      v2 = cw[col*15 + k0+2];
      v3 = (k0+3 < 15) ? cw[col*15 + k0+3] : 0.f;
    }
    ((float4*)cwc)[f4] = make_float4(v0, v1, v2, v3);
  }
  for (int idx = tid; idx < 7680; idx += 1024) {
    const int e = idx & 3;
    const int f4 = idx >> 2;
    const int j4 = f4 % 15;
    const int col = f4 / 15;
    const int j = 4*j4 + e;
    w2T[idx] = (j < 60 && col < 120) ? w2[j*120 + col] : 0.f;
  }
  for (int idx = tid; idx < 640; idx += 1024) {
    const int j = idx & 63, a = idx >> 6;
    w1s[idx] = (j < 60) ? w1[a*60 + j] : 0.f;
  }
  for (int idx = tid; idx < 1440; idx += 1024) stat[idx] = 0.f;
  if (tid < 64)  b1s[tid] = (tid < 60)  ? b1[tid] : 0.f;
  if (tid < 128) b2s[tid] = (tid < 120) ? b2[tid] : 0.f;
  if (tid < 16)  cbs[tid] = (tid < 15)  ? cb[tid] : 0.f;

  const int w = tid >> 6;
  const int chunk = w >> 2;
  const int wq = w & 3;
  const int lane = tid & 63;
  const int r = lane >> 2;
  const int b = lane & 3;
  const int iraw = wq*16 + r;
  const bool valid = (iraw < 60);
  const int ii = valid ? iraw : 0;
  const int gb = blockIdx.x*4 + b;
  const int swz = (ii >> 2) & 1;

  // carries (front only reads them)
  float mu_c = 0.f, ml_c = 0.f, cu_c = 1.f, cl_c = 1.f, cs_c = 0.f;
  float tcu_r = 1.f, tcl_r = 1.f;
  if (valid) {
    mu_c = im[gb*120 + ii];
    ml_c = im[gb*120 + 60 + ii];
    cu_c = icu[gb*60 + ii];
    cl_c = icl[gb*60 + ii];
    cs_c = ics[gb*60 + ii];
    const float l0 = ltc[ii], l1 = ltc[60 + ii];
    tcu_r = (l0 >= 0.f) ? l0 + 1.f : __expf(l0);   // elup1
    tcl_r = (l1 >= 0.f) ? l1 + 1.f : __expf(l1);
  }

  const uint4*  m4u    = (const uint4*)m4b;
  const float4* cwc4   = (const float4*)cwc;
  const float4* parts4 = (const float4*)parts;

  float* o0 = out;                 // post_means  (B,T,120)
  float* o1 = out + 18432000L;     // pcu (B,T,60)
  float* o2 = out + 27648000L;     // pcl
  float* o3 = out + 36864000L;     // pcs
  float* o4 = out + 46080000L;     // prior_means (B,T,120)
  float* o5 = out + 64512000L;     // ncu
  float* o6 = out + 73728000L;     // ncl
  float* o7 = out + 82944000L;     // ncs

  __syncthreads();

  for (int t = 0; t < TT; ++t) {
    const int par = t & 1;

    // ---- phase A ----
    if (chunk == 0) {
      // front: Kalman + stat + logits partials + halving-butterfly reduce
      const long ib = (long)gb*(TT*60) + t*60 + ii;
      float obs = 0.f, ovv = 1.f;
      if (valid) { obs = lob[ib]; ovv = ovr[ib]; }
      const float denom = cu_c + ovv;
      const float inv = 1.0f / denom;
      const float qu = cu_c * inv;
      const float ql = cs_c * inv;
      const float res = obs - mu_c;
      float pm_u = mu_c + qu*res;
      float pm_l = ml_c + ql*res;
      const float f1 = 1.f - qu;
      float pcu = f1*cu_c, pcs = f1*cs_c, pcl = cl_c - ql*cs_c;
      if (!valid) { pm_u = 0.f; pm_l = 0.f; pcu = 0.f; pcs = 0.f; pcl = 0.f; }

      if (valid) {
        stat[(0*72 + ii + 3)*4 + b] = pm_u;
        stat[(1*72 + ii + 3)*4 + b] = pm_l;
        stat[(2*72 + ii + 3)*4 + b] = pcu;
        stat[(3*72 + ii + 3)*4 + b] = pcs;
        stat[(4*72 + ii + 3)*4 + b] = pcl;
      }

      float p[16];
      #pragma unroll
      for (int k = 0; k < 16; ++k) p[k] = 0.f;
      #pragma unroll
      for (int c = 0; c < 4; ++c) {
        const float4 wu = cwc4[c*128 + ii];
        const float4 wl = cwc4[c*128 + 64 + ii];
        p[c*4+0] += pm_u*wu.x + pm_l*wl.x;
        p[c*4+1] += pm_u*wu.y + pm_l*wl.y;
        p[c*4+2] += pm_u*wu.z + pm_l*wl.z;
        p[c*4+3] += pm_u*wu.w + pm_l*wl.w;
      }
      // halving butterfly over r-lanes (lane bits 2..5); b (bits 0..1) preserved.
      // After 4 stages, each lane holds the full logit for k = bitrev4(r).
      float s1[8];
      #pragma unroll
      for (int k = 0; k < 8; ++k) {
        const float send = (lane & 4) ? p[k] : p[k + 8];
        const float recv = __shfl_xor(send, 4);
        s1[k] = ((lane & 4) ? p[k + 8] : p[k]) + recv;
      }
      float s2[4];
      #pragma unroll
      for (int k = 0; k < 4; ++k) {
        const float send = (lane & 8) ? s1[k] : s1[k + 4];
        const float recv = __shfl_xor(send, 8);
        s2[k] = ((lane & 8) ? s1[k + 4] : s1[k]) + recv;
      }
      float s3[2];
      #pragma unroll
      for (int k = 0; k < 2; ++k) {
        const float send = (lane & 16) ? s2[k] : s2[k + 2];
        const float recv = __shfl_xor(send, 16);
        s3[k] = ((lane & 16) ? s2[k + 2] : s2[k]) + recv;
      }
      const float send4 = (lane & 32) ? s3[0] : s3[1];
      const float recv4 = __shfl_xor(send4, 32);
      const float stot = ((lane & 32) ? s3[1] : s3[0]) + recv4;
      const int kf = ((r & 1) << 3) | ((r & 2) << 1) | ((r & 4) >> 1) | ((r & 8) >> 3);
      parts[(wq*4 + b)*16 + kf] = stot;   // 64 distinct words -> conflict-free
    } else if (chunk == 1 || chunk == 2) {
      // ctrl MLP for batch slot wq, this chunk's column half; lane = j / col
      const int gbc = blockIdx.x*4 + wq;
      const float av = (lane < 10) ? actp[((long)gbc*TT + t)*10 + lane] : 0.f;
      float hj = b1s[lane];
      #pragma unroll
      for (int a = 0; a < 10; ++a) hj += __shfl(av, a) * w1s[a*64 + lane];
      const int hw = w - 4;
      hctl[hw*64 + lane] = (lane < 60) ? fmaxf(hj, 0.f) : 0.f;
      const int col = (chunk == 1) ? lane : 60 + lane;
      float s = (lane < 60) ? b2s[col] : 0.f;
      const float4* hb4c = (const float4*)&hctl[hw*64];
      #pragma unroll
      for (int j4 = 0; j4 < 15; ++j4)
        s += dot4(hb4c[j4], *(const float4*)&w2T[col*60 + j4*4]);
      if (lane < 60) ctl[par*528 + wq*132 + col] = s;
    }
    // c3 idle in phase A
    __syncthreads();   // B1

    // ---- c3: store post_means/post_covs from stat ----
    if (chunk == 3 && valid) {
      const long ob120 = ((long)gb*TT + t)*120;
      const long ob60  = ((long)gb*TT + t)*60;
      o0[ob120 + ii]      = stat[(0*72 + ii + 3)*4 + b];
      o0[ob120 + 60 + ii] = stat[(1*72 + ii + 3)*4 + b];
      o1[ob60 + ii] = stat[(2*72 + ii + 3)*4 + b];
      o3[ob60 + ii] = stat[(3*72 + ii + 3)*4 + b];
      o2[ob60 + ii] = stat[(4*72 + ii + 3)*4 + b];
    }

    // ---- softmax (all waves, redundant per b; round-8 proven structure) ----
    float q[16];
    #pragma unroll
    for (int k = 0; k < 16; ++k) q[k] = cbs[k];
    #pragma unroll
    for (int ww = 0; ww < 4; ++ww) {
      #pragma unroll
      for (int c = 0; c < 4; ++c) {
        const float4 pv = parts4[(ww*4 + b)*4 + c];
        q[4*c+0] += pv.x; q[4*c+1] += pv.y; q[4*c+2] += pv.z; q[4*c+3] += pv.w;
      }
    }
    float ce[16];
    #pragma unroll
    for (int k = 0; k < 15; ++k) ce[k] = __expf(q[k]);
    const float e0 = (ce[0]+ce[1]) + (ce[2]+ce[3]);
    const float e1 = (ce[4]+ce[5]) + (ce[6]+ce[7]);
    const float e2 = (ce[8]+ce[9]) + (ce[10]+ce[11]);
    const float e3 = (ce[12]+ce[13]) + ce[14];
    const float rs = 1.f / ((e0+e1) + (e2+e3));
    #pragma unroll
    for (int k = 0; k < 15; ++k) ce[k] *= rs;
    ce[15] = 0.f;
    unsigned cepk[8];
    #pragma unroll
    for (int j = 0; j < 8; ++j)
      cepk[j] = ((unsigned)bf16bits(ce[2*j+1]) << 16) | (unsigned)bf16bits(ce[2*j]);

    // ---- t-build + matvec partials, d-range per chunk ----
    float rv[5] = {0.f, 0.f, 0.f, 0.f, 0.f};
    if      (chunk == 0) tmv_part<0, 2>(m4u, cepk, stat, ii, b, swz, rv);
    else if (chunk == 1) tmv_part<2, 2>(m4u, cepk, stat, ii, b, swz, rv);
    else if (chunk == 2) tmv_part<4, 2>(m4u, cepk, stat, ii, b, swz, rv);
    else                 tmv_part<6, 1>(m4u, cepk, stat, ii, b, swz, rv);

    if (valid) {
      #pragma unroll
      for (int v = 0; v < 5; ++v) red[chunk*1280 + v*256 + ii*4 + b] = rv[v];
    }
    __syncthreads();   // B2

    // ---- combine (front: carries; c3: stores o4..o7) ----
    if (chunk == 0 || chunk == 3) {
      const float ctrl_u = ctl[par*528 + b*132 + ii];
      const float ctrl_l = ctl[par*528 + b*132 + 60 + ii];
      const int rb = ii*4 + b;
      float nmu = ctrl_u, nml = ctrl_l, ncu = tcu_r, ncl = tcl_r, ncs = 0.f;
      #pragma unroll
      for (int c = 0; c < 4; ++c) {
        nmu += red[c*1280 + 0*256 + rb];
        nml += red[c*1280 + 1*256 + rb];
        ncu += red[c*1280 + 2*256 + rb];
        ncl += red[c*1280 + 3*256 + rb];
        ncs += red[c*1280 + 4*256 + rb];
      }
      if (chunk == 3) {
        if (valid) {
          const long ob120 = ((long)gb*TT + t)*120;
          const long ob60  = ((long)gb*TT + t)*60;
          o4[ob120 + ii]      = nmu;
          o4[ob120 + 60 + ii] = nml;
          o5[ob60 + ii] = ncu;
          o6[ob60 + ii] = ncl;
          o7[ob60 + ii] = ncs;
        }
      } else {
        mu_c = nmu; ml_c = nml; cu_c = ncu; cl_c = ncl; cs_c = ncs;
      }
    }
    // races (round-8 argument): stat written pre-B1(t), read until B2(t), next
    // write after B2(t); parts written pre-B1(t), read pre-B2(t), next write
    // after B2(t); ctl parity-buffered; red written pre-B2(t), read post-B2(t),
    // next write after B1(t+1).
  }
}

} // namespace

extern "C" void kernel_launch(void* const* d_in, const int* in_sizes, int n_in,
                              void* d_out, int out_size, void* d_ws, size_t ws_size,
                              hipStream_t stream) {
  (void)in_sizes; (void)n_in; (void)d_ws; (void)ws_size; (void)out_size;
  const float* lob  = (const float*)d_in[0];
  const float* ovr  = (const float*)d_in[1];
  const float* actp = (const float*)d_in[2];
  const float* im   = (const float*)d_in[3];
  const float* icu  = (const float*)d_in[4];
  const float* icl  = (const float*)d_in[5];
  const float* ics  = (const float*)d_in[6];
  const float* tm11 = (const float*)d_in[7];
  const float* tm12 = (const float*)d_in[8];
  const float* tm21 = (const float*)d_in[9];
  const float* tm22 = (const float*)d_in[10];
  const float* cw   = (const float*)d_in[11];
  const float* cb   = (const float*)d_in[12];
  const float* w1   = (const float*)d_in[13];
  const float* b1   = (const float*)d_in[14];
  const float* w2   = (const float*)d_in[15];
  const float* b2   = (const float*)d_in[16];
  const float* ltc  = (const float*)d_in[17];

  acrkn<<<dim3(256), dim3(1024), 0, stream>>>(
      lob, ovr, actp, im, icu, icl, ics,
      tm11, tm12, tm21, tm22, cw, cb, w1, b1, w2, b2, ltc,
      (float*)d_out);
}

// Round 14
// 623.217 us; speedup vs baseline: 1.5513x; 1.0007x over previous
//
#include <hip/hip_runtime.h>
#include <hip/hip_bf16.h>

namespace {

constexpr int TT = 150;

__device__ __forceinline__ float dot4(float4 a, float4 b) {
  return a.x*b.x + a.y*b.y + a.z*b.z + a.w*b.w;
}
__device__ __forceinline__ unsigned short bf16bits(float v) {
  __hip_bfloat16 h = __float2bfloat16(v);
  return *reinterpret_cast<unsigned short*>(&h);
}
// f32 += dot of a bf16 pair (packed u32) with a bf16 pair (packed u32)
__device__ __forceinline__ float dot2bf(unsigned a, unsigned b, float c) {
  float d;
  asm("v_dot2_f32_bf16 %0, %1, %2, %3" : "=v"(d) : "v"(a), "v"(b), "v"(c));
  return d;
}
// 16-wide bf16 dot: two uint4 slots (k 0..7, 8..15) against cepk[0..7]
__device__ __forceinline__ float tdot(uint4 a, uint4 b, const unsigned* cp) {
  float s = 0.f;
  s = dot2bf(a.x, cp[0], s); s = dot2bf(a.y, cp[1], s);
  s = dot2bf(a.z, cp[2], s); s = dot2bf(a.w, cp[3], s);
  s = dot2bf(b.x, cp[4], s); s = dot2bf(b.y, cp[5], s);
  s = dot2bf(b.z, cp[6], s); s = dot2bf(b.w, cp[7], s);
  return s;
}

// t-build + banded matvec partials for d in [D0, D0+ND)
template<int D0, int ND>
__device__ __forceinline__ void tmv_part(const uint4* m4u, const unsigned* cepk,
                                         const float* stat, int ii, int b, int swz,
                                         float rv[5]) {
  #pragma unroll
  for (int dd = 0; dd < ND; ++dd) {
    const int d = D0 + dd;
    const int ba = (0*7 + d)*120 + ii*2;
    const int bb = (1*7 + d)*120 + ii*2;
    const int bc = (2*7 + d)*120 + ii*2;
    const int bd = (3*7 + d)*120 + ii*2;
    const uint4 xa = m4u[ba + swz], ya = m4u[ba + 1 - swz];
    const uint4 xb = m4u[bb + swz], yb = m4u[bb + 1 - swz];
    const uint4 xc = m4u[bc + swz], yc = m4u[bc + 1 - swz];
    const uint4 xd = m4u[bd + swz], yd = m4u[bd + 1 - swz];
    const float a11 = tdot(xa, ya, cepk);
    const float a12 = tdot(xb, yb, cepk);
    const float a21 = tdot(xc, yc, cepk);
    const float a22 = tdot(xd, yd, cepk);
    const int si = (ii + d)*4 + b;
    const float mun  = stat[si];
    const float mln  = stat[288  + si];
    const float pcun = stat[576  + si];
    const float pcsn = stat[864  + si];
    const float pcln = stat[1152 + si];
    rv[0] += a11*mun + a12*mln;
    rv[1] += a21*mun + a22*mln;
    rv[2] += a11*a11*pcun + 2.f*a11*a12*pcsn + a12*a12*pcln;
    rv[3] += a21*a21*pcun + 2.f*a21*a22*pcsn + a22*a22*pcln;
    rv[4] += a21*a11*pcun + (a22*a11 + a21*a12)*pcsn + a22*a12*pcln;
  }
}

// ---------------- single fused kernel (round-11 passing configuration) ----------------
// 1024 threads = 16 waves, 4/SIMD. chunk = w>>2:
//   c0: front (Kalman/stat/logits->parts) + t-build d{0,1} + carries
//   c1: ctrl cols 0..59 (phase A) + t-build d{2,3}
//   c2: ctrl cols 60..119 (phase A) + t-build d{4,5}
//   c3: o0..o3 stores (post-B1) + t-build d{6} + o4..o7 stores
// 2 barriers/step; softmax redundant per wave.
__launch_bounds__(1024, 4)
__global__ void acrkn(const float* __restrict__ lob,   // (B,T,60)
                      const float* __restrict__ ovr,   // (B,T,60)
                      const float* __restrict__ actp,  // (B,T,10)
                      const float* __restrict__ im,    // (B,120)
                      const float* __restrict__ icu,   // (B,60)
                      const float* __restrict__ icl,   // (B,60)
                      const float* __restrict__ ics,   // (B,60)
                      const float* __restrict__ tm11,  // (15,60,60)
                      const float* __restrict__ tm12,
                      const float* __restrict__ tm21,
                      const float* __restrict__ tm22,
                      const float* __restrict__ cw,    // (120,15)
                      const float* __restrict__ cb,    // (15)
                      const float* __restrict__ w1,    // (10,60)
                      const float* __restrict__ b1,    // (60)
                      const float* __restrict__ w2,    // (60,120)
                      const float* __restrict__ b2,    // (120)
                      const float* __restrict__ ltc,   // (120)
                      float* __restrict__ out)
{
  __shared__ __align__(16) unsigned m4b[13440];   // basis bf16x2 (53760 B)
  __shared__ __align__(16) float cwc[2048];       // logits weights (f4 = c*128+p)
  __shared__ __align__(16) float stat[1440];      // [vec][row 0..71][b]
  __shared__ __align__(16) float parts[256];      // [wq][b][k16]
  __shared__ __align__(16) float red[5120];       // [chunk][v][i<64][b]
  __shared__ __align__(16) float ctl[1056];       // [par][b][132] padded
  __shared__ __align__(16) float hctl[512];       // [w-4][j<64]
  __shared__ __align__(16) float w2T[7680];       // [col<128][j4<15][e]
  __shared__ float w1s[640];                      // [a][j<64]
  __shared__ float b1s[64];
  __shared__ float b2s[128];
  __shared__ float cbs[16];

  const int tid = threadIdx.x;

  // ---------------- one-time LDS staging ----------------
  for (int idx = tid; idx < 13440; idx += 1024) {
    const int c2 = idx & 7;
    int rest = idx >> 3;
    const int i = rest % 60;  rest /= 60;
    const int d = rest % 7;
    const int mat = rest / 7;
    const int k0 = 2*c2;
    const int j = i + d - 3;
    const float* tp = (mat == 0) ? tm11 : (mat == 1) ? tm12 : (mat == 2) ? tm21 : tm22;
    float ve = 0.f, vo = 0.f;
    if (j >= 0 && j < 60) {
      ve = tp[(k0*60 + i)*60 + j];
      if (k0 + 1 < 15) vo = tp[((k0+1)*60 + i)*60 + j];
    }
    const unsigned u = ((unsigned)bf16bits(vo) << 16) | (unsigned)bf16bits(ve);
    const int s = c2 >> 2, q = c2 & 3;
    const int sp = s ^ ((i >> 2) & 1);
    m4b[(((mat*7 + d)*60 + i)*2 + sp)*4 + q] = u;
  }
  if (tid < 512) {
    const int f4 = tid;
    const int p = f4 & 127, c = f4 >> 7;
    const int col = (p < 60) ? p : ((p >= 64 && p < 124) ? (p - 4) : -1);
    float v0 = 0.f, v1 = 0.f, v2 = 0.f, v3 = 0.f;
    if (col >= 0) {
      const int k0 = c*4;
      v0 = cw[col*15 + k0+0];
      v1 = cw[col*15 + k0+1];
      v2 = cw[col*15 + k0+2];
      v3 = (k0+3 < 15) ? cw[col*15 + k0+3] : 0.f;
    }
    ((float4*)cwc)[f4] = make_float4(v0, v1, v2, v3);
  }
  for (int idx = tid; idx < 7680; idx += 1024) {
    const int e = idx & 3;
    const int f4 = idx >> 2;
    const int j4 = f4 % 15;
    const int col = f4 / 15;
    const int j = 4*j4 + e;
    w2T[idx] = (j < 60 && col < 120) ? w2[j*120 + col] : 0.f;
  }
  for (int idx = tid; idx < 640; idx += 1024) {
    const int j = idx & 63, a = idx >> 6;
    w1s[idx] = (j < 60) ? w1[a*60 + j] : 0.f;
  }
  for (int idx = tid; idx < 1440; idx += 1024) stat[idx] = 0.f;
  if (tid < 64)  b1s[tid] = (tid < 60)  ? b1[tid] : 0.f;
  if (tid < 128) b2s[tid] = (tid < 120) ? b2[tid] : 0.f;
  if (tid < 16)  cbs[tid] = (tid < 15)  ? cb[tid] : 0.f;

  const int w = tid >> 6;
  const int chunk = w >> 2;
  const int wq = w & 3;
  const int lane = tid & 63;
  const int r = lane >> 2;
  const int b = lane & 3;
  const int iraw = wq*16 + r;
  const bool valid = (iraw < 60);
  const int ii = valid ? iraw : 0;
  const int gb = blockIdx.x*4 + b;
  const int swz = (ii >> 2) & 1;

  // carries (front only reads them)
  float mu_c = 0.f, ml_c = 0.f, cu_c = 1.f, cl_c = 1.f, cs_c = 0.f;
  float tcu_r = 1.f, tcl_r = 1.f;
  if (valid) {
    mu_c = im[gb*120 + ii];
    ml_c = im[gb*120 + 60 + ii];
    cu_c = icu[gb*60 + ii];
    cl_c = icl[gb*60 + ii];
    cs_c = ics[gb*60 + ii];
    const float l0 = ltc[ii], l1 = ltc[60 + ii];
    tcu_r = (l0 >= 0.f) ? l0 + 1.f : __expf(l0);   // elup1
    tcl_r = (l1 >= 0.f) ? l1 + 1.f : __expf(l1);
  }

  const uint4*  m4u    = (const uint4*)m4b;
  const float4* cwc4   = (const float4*)cwc;
  const float4* parts4 = (const float4*)parts;

  float* o0 = out;                 // post_means  (B,T,120)
  float* o1 = out + 18432000L;     // pcu (B,T,60)
  float* o2 = out + 27648000L;     // pcl
  float* o3 = out + 36864000L;     // pcs
  float* o4 = out + 46080000L;     // prior_means (B,T,120)
  float* o5 = out + 64512000L;     // ncu
  float* o6 = out + 73728000L;     // ncl
  float* o7 = out + 82944000L;     // ncs

  __syncthreads();

  for (int t = 0; t < TT; ++t) {
    const int par = t & 1;

    // ---- phase A ----
    if (chunk == 0) {
      // front: Kalman + stat + logits partials + halving-butterfly reduce
      const long ib = (long)gb*(TT*60) + t*60 + ii;
      float obs = 0.f, ovv = 1.f;
      if (valid) { obs = lob[ib]; ovv = ovr[ib]; }
      const float denom = cu_c + ovv;
      const float inv = 1.0f / denom;
      const float qu = cu_c * inv;
      const float ql = cs_c * inv;
      const float res = obs - mu_c;
      float pm_u = mu_c + qu*res;
      float pm_l = ml_c + ql*res;
      const float f1 = 1.f - qu;
      float pcu = f1*cu_c, pcs = f1*cs_c, pcl = cl_c - ql*cs_c;
      if (!valid) { pm_u = 0.f; pm_l = 0.f; pcu = 0.f; pcs = 0.f; pcl = 0.f; }

      if (valid) {
        stat[(0*72 + ii + 3)*4 + b] = pm_u;
        stat[(1*72 + ii + 3)*4 + b] = pm_l;
        stat[(2*72 + ii + 3)*4 + b] = pcu;
        stat[(3*72 + ii + 3)*4 + b] = pcs;
        stat[(4*72 + ii + 3)*4 + b] = pcl;
      }

      float p[16];
      #pragma unroll
      for (int k = 0; k < 16; ++k) p[k] = 0.f;
      #pragma unroll
      for (int c = 0; c < 4; ++c) {
        const float4 wu = cwc4[c*128 + ii];
        const float4 wl = cwc4[c*128 + 64 + ii];
        p[c*4+0] += pm_u*wu.x + pm_l*wl.x;
        p[c*4+1] += pm_u*wu.y + pm_l*wl.y;
        p[c*4+2] += pm_u*wu.z + pm_l*wl.z;
        p[c*4+3] += pm_u*wu.w + pm_l*wl.w;
      }
      // halving butterfly over r-lanes (lane bits 2..5); b (bits 0..1) preserved.
      float s1[8];
      #pragma unroll
      for (int k = 0; k < 8; ++k) {
        const float send = (lane & 4) ? p[k] : p[k + 8];
        const float recv = __shfl_xor(send, 4);
        s1[k] = ((lane & 4) ? p[k + 8] : p[k]) + recv;
      }
      float s2[4];
      #pragma unroll
      for (int k = 0; k < 4; ++k) {
        const float send = (lane & 8) ? s1[k] : s1[k + 4];
        const float recv = __shfl_xor(send, 8);
        s2[k] = ((lane & 8) ? s1[k + 4] : s1[k]) + recv;
      }
      float s3[2];
      #pragma unroll
      for (int k = 0; k < 2; ++k) {
        const float send = (lane & 16) ? s2[k] : s2[k + 2];
        const float recv = __shfl_xor(send, 16);
        s3[k] = ((lane & 16) ? s2[k + 2] : s2[k]) + recv;
      }
      const float send4 = (lane & 32) ? s3[0] : s3[1];
      const float recv4 = __shfl_xor(send4, 32);
      const float stot = ((lane & 32) ? s3[1] : s3[0]) + recv4;
      const int kf = ((r & 1) << 3) | ((r & 2) << 1) | ((r & 4) >> 1) | ((r & 8) >> 3);
      parts[(wq*4 + b)*16 + kf] = stot;   // 64 distinct words -> conflict-free
    } else if (chunk == 1 || chunk == 2) {
      // ctrl MLP for batch slot wq, this chunk's column half; lane = j / col
      const int gbc = blockIdx.x*4 + wq;
      const float av = (lane < 10) ? actp[((long)gbc*TT + t)*10 + lane] : 0.f;
      float hj = b1s[lane];
      #pragma unroll
      for (int a = 0; a < 10; ++a) hj += __shfl(av, a) * w1s[a*64 + lane];
      const int hw = w - 4;
      hctl[hw*64 + lane] = (lane < 60) ? fmaxf(hj, 0.f) : 0.f;
      const int col = (chunk == 1) ? lane : 60 + lane;
      float s = (lane < 60) ? b2s[col] : 0.f;
      const float4* hb4c = (const float4*)&hctl[hw*64];
      #pragma unroll
      for (int j4 = 0; j4 < 15; ++j4)
        s += dot4(hb4c[j4], *(const float4*)&w2T[col*60 + j4*4]);
      if (lane < 60) ctl[par*528 + wq*132 + col] = s;
    }
    // c3 idle in phase A
    __syncthreads();   // B1

    // ---- c3: store post_means/post_covs from stat ----
    if (chunk == 3 && valid) {
      const long ob120 = ((long)gb*TT + t)*120;
      const long ob60  = ((long)gb*TT + t)*60;
      o0[ob120 + ii]      = stat[(0*72 + ii + 3)*4 + b];
      o0[ob120 + 60 + ii] = stat[(1*72 + ii + 3)*4 + b];
      o1[ob60 + ii] = stat[(2*72 + ii + 3)*4 + b];
      o3[ob60 + ii] = stat[(3*72 + ii + 3)*4 + b];
      o2[ob60 + ii] = stat[(4*72 + ii + 3)*4 + b];
    }

    // ---- softmax (all waves, redundant per b; fixed-order read-sum) ----
    float q[16];
    #pragma unroll
    for (int k = 0; k < 16; ++k) q[k] = cbs[k];
    #pragma unroll
    for (int ww = 0; ww < 4; ++ww) {
      #pragma unroll
      for (int c = 0; c < 4; ++c) {
        const float4 pv = parts4[(ww*4 + b)*4 + c];
        q[4*c+0] += pv.x; q[4*c+1] += pv.y; q[4*c+2] += pv.z; q[4*c+3] += pv.w;
      }
    }
    float ce[16];
    #pragma unroll
    for (int k = 0; k < 15; ++k) ce[k] = __expf(q[k]);
    const float e0 = (ce[0]+ce[1]) + (ce[2]+ce[3]);
    const float e1 = (ce[4]+ce[5]) + (ce[6]+ce[7]);
    const float e2 = (ce[8]+ce[9]) + (ce[10]+ce[11]);
    const float e3 = (ce[12]+ce[13]) + ce[14];
    const float rs = 1.f / ((e0+e1) + (e2+e3));
    #pragma unroll
    for (int k = 0; k < 15; ++k) ce[k] *= rs;
    ce[15] = 0.f;
    unsigned cepk[8];
    #pragma unroll
    for (int j = 0; j < 8; ++j)
      cepk[j] = ((unsigned)bf16bits(ce[2*j+1]) << 16) | (unsigned)bf16bits(ce[2*j]);

    // ---- t-build + matvec partials, d-range per chunk ----
    float rv[5] = {0.f, 0.f, 0.f, 0.f, 0.f};
    if      (chunk == 0) tmv_part<0, 2>(m4u, cepk, stat, ii, b, swz, rv);
    else if (chunk == 1) tmv_part<2, 2>(m4u, cepk, stat, ii, b, swz, rv);
    else if (chunk == 2) tmv_part<4, 2>(m4u, cepk, stat, ii, b, swz, rv);
    else                 tmv_part<6, 1>(m4u, cepk, stat, ii, b, swz, rv);

    if (valid) {
      #pragma unroll
      for (int v = 0; v < 5; ++v) red[chunk*1280 + v*256 + ii*4 + b] = rv[v];
    }
    __syncthreads();   // B2

    // ---- combine (front: carries; c3: stores o4..o7) ----
    if (chunk == 0 || chunk == 3) {
      const float ctrl_u = ctl[par*528 + b*132 + ii];
      const float ctrl_l = ctl[par*528 + b*132 + 60 + ii];
      const int rb = ii*4 + b;
      float nmu = ctrl_u, nml = ctrl_l, ncu = tcu_r, ncl = tcl_r, ncs = 0.f;
      #pragma unroll
      for (int c = 0; c < 4; ++c) {
        nmu += red[c*1280 + 0*256 + rb];
        nml += red[c*1280 + 1*256 + rb];
        ncu += red[c*1280 + 2*256 + rb];
        ncl += red[c*1280 + 3*256 + rb];
        ncs += red[c*1280 + 4*256 + rb];
      }
      if (chunk == 3) {
        if (valid) {
          const long ob120 = ((long)gb*TT + t)*120;
          const long ob60  = ((long)gb*TT + t)*60;
          o4[ob120 + ii]      = nmu;
          o4[ob120 + 60 + ii] = nml;
          o5[ob60 + ii] = ncu;
          o6[ob60 + ii] = ncl;
          o7[ob60 + ii] = ncs;
        }
      } else {
        mu_c = nmu; ml_c = nml; cu_c = ncu; cl_c = ncl; cs_c = ncs;
      }
    }
    // races (proven in rounds 8/11): stat written pre-B1(t), read until B2(t),
    // next write after B2(t); parts written pre-B1(t), read pre-B2(t), next
    // write after B2(t); ctl parity-buffered; red written pre-B2(t), read
    // post-B2(t), next write after B1(t+1).
  }
}

} // namespace

extern "C" void kernel_launch(void* const* d_in, const int* in_sizes, int n_in,
                              void* d_out, int out_size, void* d_ws, size_t ws_size,
                              hipStream_t stream) {
  (void)in_sizes; (void)n_in; (void)d_ws; (void)ws_size; (void)out_size;
  const float* lob  = (const float*)d_in[0];
  const float* ovr  = (const float*)d_in[1];
  const float* actp = (const float*)d_in[2];
  const float* im   = (const float*)d_in[3];
  const float* icu  = (const float*)d_in[4];
  const float* icl  = (const float*)d_in[5];
  const float* ics  = (const float*)d_in[6];
  const float* tm11 = (const float*)d_in[7];
  const float* tm12 = (const float*)d_in[8];
  const float* tm21 = (const float*)d_in[9];
  const float* tm22 = (const float*)d_in[10];
  const float* cw   = (const float*)d_in[11];
  const float* cb   = (const float*)d_in[12];
  const float* w1   = (const float*)d_in[13];
  const float* b1   = (const float*)d_in[14];
  const float* w2   = (const float*)d_in[15];
  const float* b2   = (const float*)d_in[16];
  const float* ltc  = (const float*)d_in[17];

  acrkn<<<dim3(256), dim3(1024), 0, stream>>>(
      lob, ovr, actp, im, icu, icl, ics,
      tm11, tm12, tm21, tm22, cw, cb, w1, b1, w2, b2, ltc,
      (float*)d_out);
}